// Round 1
// baseline (2644.641 us; speedup 1.0000x reference)
//
#include <hip/hip_runtime.h>

#define TOTAL   160
#define NMAX    16
#define INDIM   1024
#define DIN     834
#define GF      256
#define SS      1568

__constant__ int c_counts[16] = {6,14,10,8,16,12,9,11,7,13,10,10,8,12,6,8};
__constant__ int c_offs[16]   = {0,6,20,30,38,54,66,75,86,93,106,116,126,134,146,152};

struct GemmP {
  const float* A; const float* B; float* C; const float* bias;
  int M, N, K, lda, ldb, ldc;
  int z2;
  long sA1, sA2, sB1, sB2, sC1, sC2, sb1, sb2;
  int biasMode; // 0 none, 1 col bias[n], 2 row bias[m]
  int relu;
  int Bt;       // 1: B is [N][K]; 0: B is [K][N]
};

// Generic fp32 tiled GEMM: C[m,n] = act( sum_k A[m,k]*B(k,n) + bias )
// Tile 64x64x32, 256 threads, 4x4 micro-tile, float4 LDS fragment reads.
__global__ __launch_bounds__(256) void gemm_f32(GemmP p) {
  constexpr int BM = 64, BN = 64, BK = 32;
  __shared__ float As[BK][BM + 4];
  __shared__ float Bs[BK][BN + 4];
  const int z  = blockIdx.z;
  const int zq = z / p.z2, zr = z % p.z2;
  const float* A = p.A + zq * p.sA1 + zr * p.sA2;
  const float* B = p.B + zq * p.sB1 + zr * p.sB2;
  float*       C = p.C + zq * p.sC1 + zr * p.sC2;
  const float* bias = p.bias + zq * p.sb1 + zr * p.sb2;
  const int n0 = blockIdx.x * BN, m0 = blockIdx.y * BM;
  const int tid = threadIdx.x;
  const int tx = tid & 15, ty = tid >> 4;
  float acc[4][4] = {};
  for (int k0 = 0; k0 < p.K; k0 += BK) {
    // stage A: As[k][m] = A[m0+m][k0+k]  (coalesced along k)
    #pragma unroll
    for (int q = 0; q < 8; ++q) {
      const int idx = q * 256 + tid;
      const int kk = idx & 31, mm = idx >> 5;
      const int gm = m0 + mm, gk = k0 + kk;
      float v = 0.f;
      if (gm < p.M && gk < p.K) v = A[gm * p.lda + gk];
      As[kk][mm] = v;
    }
    if (p.Bt) {
      #pragma unroll
      for (int q = 0; q < 8; ++q) {
        const int idx = q * 256 + tid;
        const int kk = idx & 31, nn = idx >> 5;
        const int gn = n0 + nn, gk = k0 + kk;
        float v = 0.f;
        if (gn < p.N && gk < p.K) v = B[gn * p.ldb + gk];
        Bs[kk][nn] = v;
      }
    } else {
      #pragma unroll
      for (int q = 0; q < 8; ++q) {
        const int idx = q * 256 + tid;
        const int nn = idx & 63, kk = idx >> 6;
        const int gn = n0 + nn, gk = k0 + kk;
        float v = 0.f;
        if (gn < p.N && gk < p.K) v = B[gk * p.ldb + gn];
        Bs[kk][nn] = v;
      }
    }
    __syncthreads();
    #pragma unroll
    for (int k = 0; k < BK; ++k) {
      const float4 av = *reinterpret_cast<const float4*>(&As[k][ty << 2]);
      const float4 bv = *reinterpret_cast<const float4*>(&Bs[k][tx << 2]);
      const float a[4] = {av.x, av.y, av.z, av.w};
      const float b[4] = {bv.x, bv.y, bv.z, bv.w};
      #pragma unroll
      for (int i = 0; i < 4; ++i)
        #pragma unroll
        for (int j = 0; j < 4; ++j)
          acc[i][j] = fmaf(a[i], b[j], acc[i][j]);
    }
    __syncthreads();
  }
  #pragma unroll
  for (int i = 0; i < 4; ++i) {
    const int m = m0 + (ty << 2) + i;
    if (m >= p.M) continue;
    #pragma unroll
    for (int j = 0; j < 4; ++j) {
      const int n = n0 + (tx << 2) + j;
      if (n >= p.N) continue;
      float v = acc[i][j];
      if (p.biasMode == 1) v += bias[n];
      else if (p.biasMode == 2) v += bias[m];
      if (p.relu) v = fmaxf(v, 0.f);
      C[m * p.ldc + n] = v;
    }
  }
}

// Per (g,b) block: logits[n][s] = sum_f emb[n][f]*ctx[f][s]; write raw logits
// to Padj; online softmax stats (max, sum) -> mstat[z][0..15]=max, [16..31]=1/sum.
__global__ __launch_bounds__(256) void adj_logits_kernel(
    const float* __restrict__ emb, const float* __restrict__ ctx,
    float* __restrict__ Padj, float* __restrict__ mstat)
{
  __shared__ float embT[GF][16];
  __shared__ float redm[4][16];
  __shared__ float redl[4][16];
  const int z = blockIdx.x;
  const int g = z >> 4, b = z & 15;
  const int count = c_counts[b], off = c_offs[b];
  const float* ctxz = ctx + (size_t)z * GF * SS;
  float* Pz = Padj + (size_t)z * NMAX * SS;
  const int tid = threadIdx.x;

  #pragma unroll
  for (int n = 0; n < 16; ++n) {
    float v = 0.f;
    if (n < count) v = emb[(off + n) * INDIM + (g << 8) + tid];
    embT[tid][n] = v;
  }
  __syncthreads();

  float mrun[16], lrun[16];
  #pragma unroll
  for (int n = 0; n < 16; ++n) { mrun[n] = -3.0e38f; lrun[n] = 0.f; }

  for (int c = 0; c < 4; ++c) {
    const int s = (c * 256 + tid) * 2;
    if (s < SS) {
      float a0[16] = {}, a1[16] = {};
      #pragma unroll 4
      for (int f = 0; f < GF; ++f) {
        const float2 cv = *reinterpret_cast<const float2*>(&ctxz[f * SS + s]);
        const float4* er = reinterpret_cast<const float4*>(&embT[f][0]);
        const float4 e0 = er[0], e1 = er[1], e2 = er[2], e3 = er[3];
        const float ev[16] = {e0.x,e0.y,e0.z,e0.w, e1.x,e1.y,e1.z,e1.w,
                              e2.x,e2.y,e2.z,e2.w, e3.x,e3.y,e3.z,e3.w};
        #pragma unroll
        for (int n = 0; n < 16; ++n) {
          a0[n] = fmaf(ev[n], cv.x, a0[n]);
          a1[n] = fmaf(ev[n], cv.y, a1[n]);
        }
      }
      #pragma unroll
      for (int n = 0; n < 16; ++n) {
        float2 st; st.x = a0[n]; st.y = a1[n];
        *reinterpret_cast<float2*>(&Pz[n * SS + s]) = st;
        const float mx = fmaxf(a0[n], a1[n]);
        if (mx > mrun[n]) {
          lrun[n] = lrun[n] * __expf(mrun[n] - mx)
                    + __expf(a0[n] - mx) + __expf(a1[n] - mx);
          mrun[n] = mx;
        } else {
          lrun[n] += __expf(a0[n] - mrun[n]) + __expf(a1[n] - mrun[n]);
        }
      }
    }
  }
  // 64-lane butterfly combine of (m,l)
  #pragma unroll
  for (int n = 0; n < 16; ++n) {
    float m = mrun[n], l = lrun[n];
    #pragma unroll
    for (int d = 1; d < 64; d <<= 1) {
      const float om = __shfl_xor(m, d, 64);
      const float ol = __shfl_xor(l, d, 64);
      const float M = fmaxf(m, om);
      l = l * __expf(m - M) + ol * __expf(om - M);
      m = M;
    }
    mrun[n] = m; lrun[n] = l;
  }
  const int wave = tid >> 6, lane = tid & 63;
  if (lane == 0) {
    #pragma unroll
    for (int n = 0; n < 16; ++n) { redm[wave][n] = mrun[n]; redl[wave][n] = lrun[n]; }
  }
  __syncthreads();
  if (tid < 16) {
    float M = -3.0e38f;
    #pragma unroll
    for (int w = 0; w < 4; ++w) M = fmaxf(M, redm[w][tid]);
    float L = 0.f;
    #pragma unroll
    for (int w = 0; w < 4; ++w) L += redl[w][tid] * __expf(redm[w][tid] - M);
    mstat[(z << 5) + tid]      = M;
    mstat[(z << 5) + 16 + tid] = 1.0f / L;
  }
  (void)count;
}

// Per (g,b) block: O[n][f] = sum_s softmax(P)[n][s]*ctx[f][s] + emb[n][f];
// write valid rows to flat.
__global__ __launch_bounds__(256) void upd_kernel(
    const float* __restrict__ emb, const float* __restrict__ ctx,
    const float* __restrict__ Padj, const float* __restrict__ mstat,
    float* __restrict__ flat)
{
  __shared__ float Bs[32][260];
  __shared__ float Ps[32][20];
  __shared__ float sm[16], sil[16];
  const int z = blockIdx.x;
  const int g = z >> 4, b = z & 15;
  const int count = c_counts[b], off = c_offs[b];
  const float* ctxz = ctx + (size_t)z * GF * SS;
  const float* Pz = Padj + (size_t)z * NMAX * SS;
  const int tid = threadIdx.x;
  if (tid < 16) sm[tid] = mstat[(z << 5) + tid];
  else if (tid < 32) sil[tid - 16] = mstat[(z << 5) + tid];
  __syncthreads();

  const int TX = tid & 63, TY = tid >> 6;
  float o[4][4] = {};
  for (int s0 = 0; s0 < SS; s0 += 32) {
    #pragma unroll
    for (int q = 0; q < 2; ++q) {
      const int idx = q * 256 + tid;
      const int ss = idx & 31, nn = idx >> 5;
      const float lg = Pz[nn * SS + s0 + ss];
      Ps[ss][nn] = __expf(lg - sm[nn]) * sil[nn];
    }
    #pragma unroll
    for (int q = 0; q < 32; ++q) {
      const int ff = (q << 3) + (tid >> 5);
      const int ss = tid & 31;
      Bs[ss][ff] = ctxz[ff * SS + s0 + ss];
    }
    __syncthreads();
    #pragma unroll
    for (int k = 0; k < 32; ++k) {
      const float4 pv = *reinterpret_cast<const float4*>(&Ps[k][TY << 2]);
      const float4 bv = *reinterpret_cast<const float4*>(&Bs[k][TX << 2]);
      const float pa[4] = {pv.x, pv.y, pv.z, pv.w};
      const float bb[4] = {bv.x, bv.y, bv.z, bv.w};
      #pragma unroll
      for (int i = 0; i < 4; ++i)
        #pragma unroll
        for (int j = 0; j < 4; ++j)
          o[i][j] = fmaf(pa[i], bb[j], o[i][j]);
    }
    __syncthreads();
  }
  #pragma unroll
  for (int i = 0; i < 4; ++i) {
    const int n = (TY << 2) + i;
    if (n < count) {
      const int t = off + n;
      const int col = (g << 8) + (TX << 2);
      const float4 e = *reinterpret_cast<const float4*>(&emb[t * INDIM + col]);
      float4 r;
      r.x = o[i][0] + e.x; r.y = o[i][1] + e.y;
      r.z = o[i][2] + e.z; r.w = o[i][3] + e.w;
      *reinterpret_cast<float4*>(&flat[t * INDIM + col]) = r;
    }
  }
}

extern "C" void kernel_launch(void* const* d_in, const int* in_sizes, int n_in,
                              void* d_out, int out_size, void* d_ws, size_t ws_size,
                              hipStream_t stream) {
  (void)in_sizes; (void)n_in; (void)out_size; (void)ws_size;
  const float* actor = (const float*)d_in[0];
  const float* fmap  = (const float*)d_in[1];
  const float* W_a   = (const float*)d_in[2];
  const float* b_a   = (const float*)d_in[3];
  const float* W_c   = (const float*)d_in[4];
  const float* b_c   = (const float*)d_in[5];
  const float* W_h   = (const float*)d_in[6];
  float* out = (float*)d_out;
  char* ws = (char*)d_ws;

  float* emb   = (float*)(ws);              // 160*1024*4      = 655,360 B
  float* flat  = (float*)(ws + 655360);     // 160*1024*4      = 655,360 B
  float* mstat = (float*)(ws + 1310720);    // 64*32*4         =   8,192 B
  float* Padj  = (float*)(ws + 1318912);    // 64*16*1568*4    = 6,422,528 B
  float* ctx   = (float*)(ws + 7741440);    // 64*256*1568*4   = 102,760,448 B

  // 1) emb = actor @ W_a^T + b_a   [160 x 1024], K=1024
  {
    GemmP p{};
    p.A = actor; p.B = W_a; p.C = emb; p.bias = b_a;
    p.M = TOTAL; p.N = INDIM; p.K = INDIM;
    p.lda = INDIM; p.ldb = INDIM; p.ldc = INDIM;
    p.z2 = 1; p.biasMode = 1; p.relu = 0; p.Bt = 1;
    hipLaunchKernelGGL(gemm_f32, dim3(16, 3, 1), dim3(256), 0, stream, p);
  }
  // 2) ctx[z=g*16+b] = W_c[g] @ fm[b] + b_c[g]   64 x [256 x 1568], K=834
  {
    GemmP p{};
    p.A = W_c; p.B = fmap; p.C = ctx; p.bias = b_c;
    p.M = GF; p.N = SS; p.K = DIN;
    p.lda = DIN; p.ldb = SS; p.ldc = SS;
    p.z2 = 16;
    p.sA1 = 256L * 834;           // per g
    p.sB2 = 834L * 1568;          // per b
    p.sC1 = 16L * 256 * 1568;     // per g
    p.sC2 = 256L * 1568;          // per b
    p.sb1 = 256;                  // per g
    p.biasMode = 2; p.relu = 0; p.Bt = 0;
    hipLaunchKernelGGL(gemm_f32, dim3(25, 4, 64), dim3(256), 0, stream, p);
  }
  // 3) logits + softmax stats
  hipLaunchKernelGGL(adj_logits_kernel, dim3(64), dim3(256), 0, stream,
                     emb, ctx, Padj, mstat);
  // 4) upd = P @ ctx^T + emb -> flat
  hipLaunchKernelGGL(upd_kernel, dim3(64), dim3(256), 0, stream,
                     emb, ctx, Padj, mstat, flat);
  // 5) out = relu(flat @ W_h^T) per g
  {
    GemmP p{};
    p.A = flat; p.B = W_h; p.C = out; p.bias = flat;
    p.M = TOTAL; p.N = GF; p.K = GF;
    p.lda = INDIM; p.ldb = GF; p.ldc = INDIM;
    p.z2 = 1;
    p.sA1 = 256; p.sB1 = 65536; p.sC1 = 256;
    p.biasMode = 0; p.relu = 1; p.Bt = 1;
    hipLaunchKernelGGL(gemm_f32, dim3(4, 3, 4), dim3(256), 0, stream, p);
  }
}

// Round 2
// 816.454 us; speedup vs baseline: 3.2392x; 3.2392x over previous
//
#include <hip/hip_runtime.h>

#define TOTAL   160
#define NMAX    16
#define INDIM   1024
#define DIN     834
#define KPAD    864
#define GF      256
#define SS      1568

__constant__ int c_counts[16] = {6,14,10,8,16,12,9,11,7,13,10,10,8,12,6,8};
__constant__ int c_offs[16]   = {0,6,20,30,38,54,66,75,86,93,106,116,126,134,146,152};

using bf16x8 = __attribute__((ext_vector_type(8))) short;
using f32x4  = __attribute__((ext_vector_type(4))) float;

__device__ inline unsigned short f2bf(float f) {
  union { float f; unsigned u; } v; v.f = f;
  const unsigned u = v.u;
  return (unsigned short)((u + 0x7FFFu + ((u >> 16) & 1u)) >> 16);
}

// ---------------- conversion kernels ----------------

__global__ __launch_bounds__(256) void wc_to_bf16(const float* __restrict__ Wc,
                                                  unsigned short* __restrict__ Ah) {
  const int idx = blockIdx.x * 256 + threadIdx.x;
  if (idx >= 4 * 256 * KPAD) return;
  const int k = idx % KPAD, gm = idx / KPAD;
  Ah[idx] = (k < DIN) ? f2bf(Wc[gm * DIN + k]) : (unsigned short)0;
}

// fm [16][834][1568] fp32 -> BhT [16][1568][864] bf16 (k-contiguous, zero-padded)
__global__ __launch_bounds__(256) void fm_to_bf16T(const float* __restrict__ fm,
                                                   unsigned short* __restrict__ BhT) {
  __shared__ float tile[32][33];
  const int b  = blockIdx.z;
  const int k0 = blockIdx.y * 32;
  const int s0 = blockIdx.x * 32;
  const int tx = threadIdx.x & 31, ty = threadIdx.x >> 5;  // ty 0..7
  const float* src = fm + (size_t)b * DIN * SS;
  #pragma unroll
  for (int r = 0; r < 4; ++r) {
    const int k = k0 + ty + r * 8;
    tile[ty + r * 8][tx] = (k < DIN) ? src[(size_t)k * SS + s0 + tx] : 0.f;
  }
  __syncthreads();
  unsigned short* dst = BhT + (size_t)b * SS * KPAD;
  #pragma unroll
  for (int r = 0; r < 4; ++r) {
    const int s = s0 + ty + r * 8;
    dst[(size_t)s * KPAD + k0 + tx] = f2bf(tile[tx][ty + r * 8]);
  }
}

// ---------------- bf16 MFMA GEMM for ctx ----------------
// ctx[z=g*16+b][m][n] = sum_k Wc[g][m][k] * fm[b][k][n] + b_c[g][m]
// A = Ah [g][256][864] bf16 (k-contig); B = BhT [b][1568][864] bf16 (k-contig)
__global__ __launch_bounds__(256, 2) void ctx_mfma(const unsigned short* __restrict__ Ah,
                                                   const unsigned short* __restrict__ BhT,
                                                   const float* __restrict__ b_c,
                                                   float* __restrict__ ctx) {
  __shared__ unsigned short As[128 * 40];  // rows m, 32 k + 8 pad
  __shared__ unsigned short Bs[128 * 40];  // rows n, 32 k + 8 pad
  const int z = blockIdx.z, g = z >> 4, b = z & 15;
  const int n0 = blockIdx.x * 128, m0 = blockIdx.y * 128;
  const int tid = threadIdx.x;
  const int wave = tid >> 6, lane = tid & 63;
  const int wm = (wave >> 1) * 64, wn = (wave & 1) * 64;
  const int quad = lane >> 4, lr = lane & 15;

  const unsigned short* Ag = Ah + (size_t)g * 256 * KPAD + (size_t)m0 * KPAD;
  const unsigned short* Bg = BhT + (size_t)b * SS * KPAD;

  const int c0 = tid, c1 = tid + 256;           // chunk ids; r=c>>2, ko=(c&3)*8
  const int r0 = c0 >> 2, ko0 = (c0 & 3) * 8;
  const int r1 = c1 >> 2, ko1 = (c1 & 3) * 8;

  f32x4 acc[4][4];
  #pragma unroll
  for (int i = 0; i < 4; ++i)
    #pragma unroll
    for (int j = 0; j < 4; ++j) acc[i][j] = (f32x4){0.f, 0.f, 0.f, 0.f};

  const uint4 zero4 = {0u, 0u, 0u, 0u};
  uint4 ra0, ra1, rb0, rb1;
  {
    ra0 = *reinterpret_cast<const uint4*>(Ag + (size_t)r0 * KPAD + ko0);
    ra1 = *reinterpret_cast<const uint4*>(Ag + (size_t)r1 * KPAD + ko1);
    rb0 = (n0 + r0 < SS) ? *reinterpret_cast<const uint4*>(Bg + (size_t)(n0 + r0) * KPAD + ko0) : zero4;
    rb1 = (n0 + r1 < SS) ? *reinterpret_cast<const uint4*>(Bg + (size_t)(n0 + r1) * KPAD + ko1) : zero4;
  }

  for (int kt = 0; kt < 27; ++kt) {
    __syncthreads();
    *reinterpret_cast<uint4*>(&As[r0 * 40 + ko0]) = ra0;
    *reinterpret_cast<uint4*>(&As[r1 * 40 + ko1]) = ra1;
    *reinterpret_cast<uint4*>(&Bs[r0 * 40 + ko0]) = rb0;
    *reinterpret_cast<uint4*>(&Bs[r1 * 40 + ko1]) = rb1;
    __syncthreads();
    if (kt < 26) {
      const int k0 = (kt + 1) * 32;
      ra0 = *reinterpret_cast<const uint4*>(Ag + (size_t)r0 * KPAD + k0 + ko0);
      ra1 = *reinterpret_cast<const uint4*>(Ag + (size_t)r1 * KPAD + k0 + ko1);
      rb0 = (n0 + r0 < SS) ? *reinterpret_cast<const uint4*>(Bg + (size_t)(n0 + r0) * KPAD + k0 + ko0) : zero4;
      rb1 = (n0 + r1 < SS) ? *reinterpret_cast<const uint4*>(Bg + (size_t)(n0 + r1) * KPAD + k0 + ko1) : zero4;
    }
    bf16x8 af[4], bfr[4];
    #pragma unroll
    for (int i = 0; i < 4; ++i)
      af[i] = *reinterpret_cast<const bf16x8*>(&As[(wm + i * 16 + lr) * 40 + quad * 8]);
    #pragma unroll
    for (int j = 0; j < 4; ++j)
      bfr[j] = *reinterpret_cast<const bf16x8*>(&Bs[(wn + j * 16 + lr) * 40 + quad * 8]);
    #pragma unroll
    for (int i = 0; i < 4; ++i)
      #pragma unroll
      for (int j = 0; j < 4; ++j)
        acc[i][j] = __builtin_amdgcn_mfma_f32_16x16x32_bf16(af[i], bfr[j], acc[i][j], 0, 0, 0);
  }

  float* Cz = ctx + (size_t)z * GF * SS;
  const float* bias = b_c + g * GF;
  #pragma unroll
  for (int i = 0; i < 4; ++i) {
    #pragma unroll
    for (int reg = 0; reg < 4; ++reg) {
      const int m = m0 + wm + i * 16 + quad * 4 + reg;
      const float bv = bias[m];
      #pragma unroll
      for (int j = 0; j < 4; ++j) {
        const int n = n0 + wn + j * 16 + lr;
        if (n < SS) Cz[(size_t)m * SS + n] = acc[i][j][reg] + bv;
      }
    }
  }
}

// ---------------- generic fp32 GEMM (emb, head) ----------------

struct GemmP {
  const float* A; const float* B; float* C; const float* bias;
  int M, N, K, lda, ldb, ldc;
  int z2;
  long sA1, sA2, sB1, sB2, sC1, sC2, sb1, sb2;
  int biasMode; // 0 none, 1 col bias[n], 2 row bias[m]
  int relu;
  int Bt;       // 1: B is [N][K]; 0: B is [K][N]
};

__global__ __launch_bounds__(256) void gemm_f32(GemmP p) {
  constexpr int BM = 64, BN = 64, BK = 32;
  __shared__ float As[BK][BM + 4];
  __shared__ float Bs[BK][BN + 4];
  const int z  = blockIdx.z;
  const int zq = z / p.z2, zr = z % p.z2;
  const float* A = p.A + zq * p.sA1 + zr * p.sA2;
  const float* B = p.B + zq * p.sB1 + zr * p.sB2;
  float*       C = p.C + zq * p.sC1 + zr * p.sC2;
  const float* bias = p.bias + zq * p.sb1 + zr * p.sb2;
  const int n0 = blockIdx.x * BN, m0 = blockIdx.y * BM;
  const int tid = threadIdx.x;
  const int tx = tid & 15, ty = tid >> 4;
  float acc[4][4] = {};
  for (int k0 = 0; k0 < p.K; k0 += BK) {
    #pragma unroll
    for (int q = 0; q < 8; ++q) {
      const int idx = q * 256 + tid;
      const int kk = idx & 31, mm = idx >> 5;
      const int gm = m0 + mm, gk = k0 + kk;
      float v = 0.f;
      if (gm < p.M && gk < p.K) v = A[gm * p.lda + gk];
      As[kk][mm] = v;
    }
    if (p.Bt) {
      #pragma unroll
      for (int q = 0; q < 8; ++q) {
        const int idx = q * 256 + tid;
        const int kk = idx & 31, nn = idx >> 5;
        const int gn = n0 + nn, gk = k0 + kk;
        float v = 0.f;
        if (gn < p.N && gk < p.K) v = B[gn * p.ldb + gk];
        Bs[kk][nn] = v;
      }
    } else {
      #pragma unroll
      for (int q = 0; q < 8; ++q) {
        const int idx = q * 256 + tid;
        const int nn = idx & 63, kk = idx >> 6;
        const int gn = n0 + nn, gk = k0 + kk;
        float v = 0.f;
        if (gn < p.N && gk < p.K) v = B[gk * p.ldb + gn];
        Bs[kk][nn] = v;
      }
    }
    __syncthreads();
    #pragma unroll
    for (int k = 0; k < BK; ++k) {
      const float4 av = *reinterpret_cast<const float4*>(&As[k][ty << 2]);
      const float4 bv = *reinterpret_cast<const float4*>(&Bs[k][tx << 2]);
      const float a[4] = {av.x, av.y, av.z, av.w};
      const float b[4] = {bv.x, bv.y, bv.z, bv.w};
      #pragma unroll
      for (int i = 0; i < 4; ++i)
        #pragma unroll
        for (int j = 0; j < 4; ++j)
          acc[i][j] = fmaf(a[i], b[j], acc[i][j]);
    }
    __syncthreads();
  }
  #pragma unroll
  for (int i = 0; i < 4; ++i) {
    const int m = m0 + (ty << 2) + i;
    if (m >= p.M) continue;
    #pragma unroll
    for (int j = 0; j < 4; ++j) {
      const int n = n0 + (tx << 2) + j;
      if (n >= p.N) continue;
      float v = acc[i][j];
      if (p.biasMode == 1) v += bias[n];
      else if (p.biasMode == 2) v += bias[m];
      if (p.relu) v = fmaxf(v, 0.f);
      C[m * p.ldc + n] = v;
    }
  }
}

// ---------------- adj logits + softmax stats ----------------

__global__ __launch_bounds__(256) void adj_logits_kernel(
    const float* __restrict__ emb, const float* __restrict__ ctx,
    float* __restrict__ Padj, float* __restrict__ mstat)
{
  __shared__ float embT[GF][16];
  __shared__ float redm[4][16];
  __shared__ float redl[4][16];
  const int z = blockIdx.x;
  const int g = z >> 4, b = z & 15;
  const int count = c_counts[b], off = c_offs[b];
  const float* ctxz = ctx + (size_t)z * GF * SS;
  float* Pz = Padj + (size_t)z * NMAX * SS;
  const int tid = threadIdx.x;

  #pragma unroll
  for (int n = 0; n < 16; ++n) {
    float v = 0.f;
    if (n < count) v = emb[(off + n) * INDIM + (g << 8) + tid];
    embT[tid][n] = v;
  }
  __syncthreads();

  float mrun[16], lrun[16];
  #pragma unroll
  for (int n = 0; n < 16; ++n) { mrun[n] = -3.0e38f; lrun[n] = 0.f; }

  for (int c = 0; c < 4; ++c) {
    const int s = (c * 256 + tid) * 2;
    if (s < SS) {
      float a0[16] = {}, a1[16] = {};
      #pragma unroll 4
      for (int f = 0; f < GF; ++f) {
        const float2 cv = *reinterpret_cast<const float2*>(&ctxz[f * SS + s]);
        const float4* er = reinterpret_cast<const float4*>(&embT[f][0]);
        const float4 e0 = er[0], e1 = er[1], e2 = er[2], e3 = er[3];
        const float ev[16] = {e0.x,e0.y,e0.z,e0.w, e1.x,e1.y,e1.z,e1.w,
                              e2.x,e2.y,e2.z,e2.w, e3.x,e3.y,e3.z,e3.w};
        #pragma unroll
        for (int n = 0; n < 16; ++n) {
          a0[n] = fmaf(ev[n], cv.x, a0[n]);
          a1[n] = fmaf(ev[n], cv.y, a1[n]);
        }
      }
      #pragma unroll
      for (int n = 0; n < 16; ++n) {
        float2 st; st.x = a0[n]; st.y = a1[n];
        *reinterpret_cast<float2*>(&Pz[n * SS + s]) = st;
        const float mx = fmaxf(a0[n], a1[n]);
        if (mx > mrun[n]) {
          lrun[n] = lrun[n] * __expf(mrun[n] - mx)
                    + __expf(a0[n] - mx) + __expf(a1[n] - mx);
          mrun[n] = mx;
        } else {
          lrun[n] += __expf(a0[n] - mrun[n]) + __expf(a1[n] - mrun[n]);
        }
      }
    }
  }
  #pragma unroll
  for (int n = 0; n < 16; ++n) {
    float m = mrun[n], l = lrun[n];
    #pragma unroll
    for (int d = 1; d < 64; d <<= 1) {
      const float om = __shfl_xor(m, d, 64);
      const float ol = __shfl_xor(l, d, 64);
      const float M = fmaxf(m, om);
      l = l * __expf(m - M) + ol * __expf(om - M);
      m = M;
    }
    mrun[n] = m; lrun[n] = l;
  }
  const int wave = tid >> 6, lane = tid & 63;
  if (lane == 0) {
    #pragma unroll
    for (int n = 0; n < 16; ++n) { redm[wave][n] = mrun[n]; redl[wave][n] = lrun[n]; }
  }
  __syncthreads();
  if (tid < 16) {
    float M = -3.0e38f;
    #pragma unroll
    for (int w = 0; w < 4; ++w) M = fmaxf(M, redm[w][tid]);
    float L = 0.f;
    #pragma unroll
    for (int w = 0; w < 4; ++w) L += redl[w][tid] * __expf(redm[w][tid] - M);
    mstat[(z << 5) + tid]      = M;
    mstat[(z << 5) + 16 + tid] = 1.0f / L;
  }
  (void)count;
}

// ---------------- upd = P @ ctx^T + emb ----------------

__global__ __launch_bounds__(256) void upd_kernel(
    const float* __restrict__ emb, const float* __restrict__ ctx,
    const float* __restrict__ Padj, const float* __restrict__ mstat,
    float* __restrict__ flat)
{
  __shared__ float Bs[32][260];
  __shared__ float Ps[32][20];
  __shared__ float sm[16], sil[16];
  const int z = blockIdx.x;
  const int g = z >> 4, b = z & 15;
  const int count = c_counts[b], off = c_offs[b];
  const float* ctxz = ctx + (size_t)z * GF * SS;
  const float* Pz = Padj + (size_t)z * NMAX * SS;
  const int tid = threadIdx.x;
  if (tid < 16) sm[tid] = mstat[(z << 5) + tid];
  else if (tid < 32) sil[tid - 16] = mstat[(z << 5) + tid];
  __syncthreads();

  const int TX = tid & 63, TY = tid >> 6;
  float o[4][4] = {};
  for (int s0 = 0; s0 < SS; s0 += 32) {
    #pragma unroll
    for (int q = 0; q < 2; ++q) {
      const int idx = q * 256 + tid;
      const int ss = idx & 31, nn = idx >> 5;
      const float lg = Pz[nn * SS + s0 + ss];
      Ps[ss][nn] = __expf(lg - sm[nn]) * sil[nn];
    }
    #pragma unroll
    for (int q = 0; q < 32; ++q) {
      const int ff = (q << 3) + (tid >> 5);
      const int ss = tid & 31;
      Bs[ss][ff] = ctxz[ff * SS + s0 + ss];
    }
    __syncthreads();
    #pragma unroll
    for (int k = 0; k < 32; ++k) {
      const float4 pv = *reinterpret_cast<const float4*>(&Ps[k][TY << 2]);
      const float4 bv = *reinterpret_cast<const float4*>(&Bs[k][TX << 2]);
      const float pa[4] = {pv.x, pv.y, pv.z, pv.w};
      const float bb[4] = {bv.x, bv.y, bv.z, bv.w};
      #pragma unroll
      for (int i = 0; i < 4; ++i)
        #pragma unroll
        for (int j = 0; j < 4; ++j)
          o[i][j] = fmaf(pa[i], bb[j], o[i][j]);
    }
    __syncthreads();
  }
  #pragma unroll
  for (int i = 0; i < 4; ++i) {
    const int n = (TY << 2) + i;
    if (n < count) {
      const int t = off + n;
      const int col = (g << 8) + (TX << 2);
      const float4 e = *reinterpret_cast<const float4*>(&emb[t * INDIM + col]);
      float4 r;
      r.x = o[i][0] + e.x; r.y = o[i][1] + e.y;
      r.z = o[i][2] + e.z; r.w = o[i][3] + e.w;
      *reinterpret_cast<float4*>(&flat[t * INDIM + col]) = r;
    }
  }
}

extern "C" void kernel_launch(void* const* d_in, const int* in_sizes, int n_in,
                              void* d_out, int out_size, void* d_ws, size_t ws_size,
                              hipStream_t stream) {
  (void)in_sizes; (void)n_in; (void)out_size; (void)ws_size;
  const float* actor = (const float*)d_in[0];
  const float* fmap  = (const float*)d_in[1];
  const float* W_a   = (const float*)d_in[2];
  const float* b_a   = (const float*)d_in[3];
  const float* W_c   = (const float*)d_in[4];
  const float* b_c   = (const float*)d_in[5];
  const float* W_h   = (const float*)d_in[6];
  float* out = (float*)d_out;
  char* ws = (char*)d_ws;

  float* emb   = (float*)(ws);                     // 655,360 B
  float* flat  = (float*)(ws + 655360);            // 655,360 B
  float* mstat = (float*)(ws + 1310720);           //   8,192 B
  float* Padj  = (float*)(ws + 1318912);           // 6,422,528 B
  float* ctx   = (float*)(ws + 7741440);           // 102,760,448 B
  unsigned short* Ah  = (unsigned short*)(ws + 110501888);  // 4*256*864*2 = 1,769,472 B
  unsigned short* BhT = (unsigned short*)(ws + 112271360);  // 16*1568*864*2 = 43,352,064 B

  // 0) bf16 conversions for the big GEMM
  hipLaunchKernelGGL(wc_to_bf16, dim3((4 * 256 * KPAD + 255) / 256), dim3(256), 0, stream,
                     W_c, Ah);
  hipLaunchKernelGGL(fm_to_bf16T, dim3(49, 27, 16), dim3(256), 0, stream, fmap, BhT);

  // 1) emb = actor @ W_a^T + b_a   [160 x 1024], K=1024 (fp32)
  {
    GemmP p{};
    p.A = actor; p.B = W_a; p.C = emb; p.bias = b_a;
    p.M = TOTAL; p.N = INDIM; p.K = INDIM;
    p.lda = INDIM; p.ldb = INDIM; p.ldc = INDIM;
    p.z2 = 1; p.biasMode = 1; p.relu = 0; p.Bt = 1;
    hipLaunchKernelGGL(gemm_f32, dim3(16, 3, 1), dim3(256), 0, stream, p);
  }
  // 2) ctx via bf16 MFMA
  hipLaunchKernelGGL(ctx_mfma, dim3(13, 2, 64), dim3(256), 0, stream, Ah, BhT, b_c, ctx);
  // 3) logits + softmax stats
  hipLaunchKernelGGL(adj_logits_kernel, dim3(64), dim3(256), 0, stream,
                     emb, ctx, Padj, mstat);
  // 4) upd = P @ ctx^T + emb -> flat
  hipLaunchKernelGGL(upd_kernel, dim3(64), dim3(256), 0, stream,
                     emb, ctx, Padj, mstat, flat);
  // 5) out = relu(flat @ W_h^T) per g (fp32)
  {
    GemmP p{};
    p.A = flat; p.B = W_h; p.C = out; p.bias = flat;
    p.M = TOTAL; p.N = GF; p.K = GF;
    p.lda = INDIM; p.ldb = GF; p.ldc = INDIM;
    p.z2 = 1;
    p.sA1 = 256; p.sB1 = 65536; p.sC1 = 256;
    p.biasMode = 0; p.relu = 1; p.Bt = 1;
    hipLaunchKernelGGL(gemm_f32, dim3(4, 3, 4), dim3(256), 0, stream, p);
  }
}

// Round 3
// 637.521 us; speedup vs baseline: 4.1483x; 1.2807x over previous
//
#include <hip/hip_runtime.h>

#define TOTAL   160
#define NMAX    16
#define INDIM   1024
#define DIN     834
#define KPAD    864
#define GF      256
#define SS      1568
#define SCH     196   // s-chunk for adj_part (8 * 196 = 1568)

__constant__ int c_counts[16] = {6,14,10,8,16,12,9,11,7,13,10,10,8,12,6,8};
__constant__ int c_offs[16]   = {0,6,20,30,38,54,66,75,86,93,106,116,126,134,146,152};

using bf16x8 = __attribute__((ext_vector_type(8))) short;
using f32x4  = __attribute__((ext_vector_type(4))) float;

__device__ inline unsigned short f2bf(float f) {
  union { float f; unsigned u; } v; v.f = f;
  const unsigned u = v.u;
  return (unsigned short)((u + 0x7FFFu + ((u >> 16) & 1u)) >> 16);
}

// ---------------- conversion kernels ----------------

__global__ __launch_bounds__(256) void wc_to_bf16(const float* __restrict__ Wc,
                                                  unsigned short* __restrict__ Ah) {
  const int idx = blockIdx.x * 256 + threadIdx.x;
  if (idx >= 4 * 256 * KPAD) return;
  const int k = idx % KPAD, gm = idx / KPAD;
  Ah[idx] = (k < DIN) ? f2bf(Wc[gm * DIN + k]) : (unsigned short)0;
}

// fm [16][834][1568] fp32 -> BhT [16][1568][864] bf16 (k-contiguous, zero-padded)
__global__ __launch_bounds__(256) void fm_to_bf16T(const float* __restrict__ fm,
                                                   unsigned short* __restrict__ BhT) {
  __shared__ float tile[32][33];
  const int b  = blockIdx.z;
  const int k0 = blockIdx.y * 32;
  const int s0 = blockIdx.x * 32;
  const int tx = threadIdx.x & 31, ty = threadIdx.x >> 5;  // ty 0..7
  const float* src = fm + (size_t)b * DIN * SS;
  #pragma unroll
  for (int r = 0; r < 4; ++r) {
    const int k = k0 + ty + r * 8;
    tile[ty + r * 8][tx] = (k < DIN) ? src[(size_t)k * SS + s0 + tx] : 0.f;
  }
  __syncthreads();
  unsigned short* dst = BhT + (size_t)b * SS * KPAD;
  #pragma unroll
  for (int r = 0; r < 4; ++r) {
    const int s = s0 + ty + r * 8;
    dst[(size_t)s * KPAD + k0 + tx] = f2bf(tile[tx][ty + r * 8]);
  }
}

// ---------------- bf16 MFMA GEMM for ctx ----------------

__global__ __launch_bounds__(256, 2) void ctx_mfma(const unsigned short* __restrict__ Ah,
                                                   const unsigned short* __restrict__ BhT,
                                                   const float* __restrict__ b_c,
                                                   float* __restrict__ ctx) {
  __shared__ unsigned short As[128 * 40];
  __shared__ unsigned short Bs[128 * 40];
  const int z = blockIdx.z, g = z >> 4, b = z & 15;
  const int n0 = blockIdx.x * 128, m0 = blockIdx.y * 128;
  const int tid = threadIdx.x;
  const int wave = tid >> 6, lane = tid & 63;
  const int wm = (wave >> 1) * 64, wn = (wave & 1) * 64;
  const int quad = lane >> 4, lr = lane & 15;

  const unsigned short* Ag = Ah + (size_t)g * 256 * KPAD + (size_t)m0 * KPAD;
  const unsigned short* Bg = BhT + (size_t)b * SS * KPAD;

  const int c0 = tid, c1 = tid + 256;
  const int r0 = c0 >> 2, ko0 = (c0 & 3) * 8;
  const int r1 = c1 >> 2, ko1 = (c1 & 3) * 8;

  f32x4 acc[4][4];
  #pragma unroll
  for (int i = 0; i < 4; ++i)
    #pragma unroll
    for (int j = 0; j < 4; ++j) acc[i][j] = (f32x4){0.f, 0.f, 0.f, 0.f};

  const uint4 zero4 = {0u, 0u, 0u, 0u};
  uint4 ra0, ra1, rb0, rb1;
  {
    ra0 = *reinterpret_cast<const uint4*>(Ag + (size_t)r0 * KPAD + ko0);
    ra1 = *reinterpret_cast<const uint4*>(Ag + (size_t)r1 * KPAD + ko1);
    rb0 = (n0 + r0 < SS) ? *reinterpret_cast<const uint4*>(Bg + (size_t)(n0 + r0) * KPAD + ko0) : zero4;
    rb1 = (n0 + r1 < SS) ? *reinterpret_cast<const uint4*>(Bg + (size_t)(n0 + r1) * KPAD + ko1) : zero4;
  }

  for (int kt = 0; kt < 27; ++kt) {
    __syncthreads();
    *reinterpret_cast<uint4*>(&As[r0 * 40 + ko0]) = ra0;
    *reinterpret_cast<uint4*>(&As[r1 * 40 + ko1]) = ra1;
    *reinterpret_cast<uint4*>(&Bs[r0 * 40 + ko0]) = rb0;
    *reinterpret_cast<uint4*>(&Bs[r1 * 40 + ko1]) = rb1;
    __syncthreads();
    if (kt < 26) {
      const int k0 = (kt + 1) * 32;
      ra0 = *reinterpret_cast<const uint4*>(Ag + (size_t)r0 * KPAD + k0 + ko0);
      ra1 = *reinterpret_cast<const uint4*>(Ag + (size_t)r1 * KPAD + k0 + ko1);
      rb0 = (n0 + r0 < SS) ? *reinterpret_cast<const uint4*>(Bg + (size_t)(n0 + r0) * KPAD + k0 + ko0) : zero4;
      rb1 = (n0 + r1 < SS) ? *reinterpret_cast<const uint4*>(Bg + (size_t)(n0 + r1) * KPAD + k0 + ko1) : zero4;
    }
    bf16x8 af[4], bfr[4];
    #pragma unroll
    for (int i = 0; i < 4; ++i)
      af[i] = *reinterpret_cast<const bf16x8*>(&As[(wm + i * 16 + lr) * 40 + quad * 8]);
    #pragma unroll
    for (int j = 0; j < 4; ++j)
      bfr[j] = *reinterpret_cast<const bf16x8*>(&Bs[(wn + j * 16 + lr) * 40 + quad * 8]);
    #pragma unroll
    for (int i = 0; i < 4; ++i)
      #pragma unroll
      for (int j = 0; j < 4; ++j)
        acc[i][j] = __builtin_amdgcn_mfma_f32_16x16x32_bf16(af[i], bfr[j], acc[i][j], 0, 0, 0);
  }

  float* Cz = ctx + (size_t)z * GF * SS;
  const float* bias = b_c + g * GF;
  #pragma unroll
  for (int i = 0; i < 4; ++i) {
    #pragma unroll
    for (int reg = 0; reg < 4; ++reg) {
      const int m = m0 + wm + i * 16 + quad * 4 + reg;
      const float bv = bias[m];
      #pragma unroll
      for (int j = 0; j < 4; ++j) {
        const int n = n0 + wn + j * 16 + lr;
        if (n < SS) Cz[(size_t)m * SS + n] = acc[i][j][reg] + bv;
      }
    }
  }
}

// ---------------- generic fp32 GEMM (emb, head) ----------------

struct GemmP {
  const float* A; const float* B; float* C; const float* bias;
  int M, N, K, lda, ldb, ldc;
  int z2;
  long sA1, sA2, sB1, sB2, sC1, sC2, sb1, sb2;
  int biasMode;
  int relu;
  int Bt;
};

__global__ __launch_bounds__(256) void gemm_f32(GemmP p) {
  constexpr int BM = 64, BN = 64, BK = 32;
  __shared__ float As[BK][BM + 4];
  __shared__ float Bs[BK][BN + 4];
  const int z  = blockIdx.z;
  const int zq = z / p.z2, zr = z % p.z2;
  const float* A = p.A + zq * p.sA1 + zr * p.sA2;
  const float* B = p.B + zq * p.sB1 + zr * p.sB2;
  float*       C = p.C + zq * p.sC1 + zr * p.sC2;
  const float* bias = p.bias + zq * p.sb1 + zr * p.sb2;
  const int n0 = blockIdx.x * BN, m0 = blockIdx.y * BM;
  const int tid = threadIdx.x;
  const int tx = tid & 15, ty = tid >> 4;
  float acc[4][4] = {};
  for (int k0 = 0; k0 < p.K; k0 += BK) {
    #pragma unroll
    for (int q = 0; q < 8; ++q) {
      const int idx = q * 256 + tid;
      const int kk = idx & 31, mm = idx >> 5;
      const int gm = m0 + mm, gk = k0 + kk;
      float v = 0.f;
      if (gm < p.M && gk < p.K) v = A[gm * p.lda + gk];
      As[kk][mm] = v;
    }
    if (p.Bt) {
      #pragma unroll
      for (int q = 0; q < 8; ++q) {
        const int idx = q * 256 + tid;
        const int kk = idx & 31, nn = idx >> 5;
        const int gn = n0 + nn, gk = k0 + kk;
        float v = 0.f;
        if (gn < p.N && gk < p.K) v = B[gn * p.ldb + gk];
        Bs[kk][nn] = v;
      }
    } else {
      #pragma unroll
      for (int q = 0; q < 8; ++q) {
        const int idx = q * 256 + tid;
        const int nn = idx & 63, kk = idx >> 6;
        const int gn = n0 + nn, gk = k0 + kk;
        float v = 0.f;
        if (gn < p.N && gk < p.K) v = B[gk * p.ldb + gn];
        Bs[kk][nn] = v;
      }
    }
    __syncthreads();
    #pragma unroll
    for (int k = 0; k < BK; ++k) {
      const float4 av = *reinterpret_cast<const float4*>(&As[k][ty << 2]);
      const float4 bv = *reinterpret_cast<const float4*>(&Bs[k][tx << 2]);
      const float a[4] = {av.x, av.y, av.z, av.w};
      const float b[4] = {bv.x, bv.y, bv.z, bv.w};
      #pragma unroll
      for (int i = 0; i < 4; ++i)
        #pragma unroll
        for (int j = 0; j < 4; ++j)
          acc[i][j] = fmaf(a[i], b[j], acc[i][j]);
    }
    __syncthreads();
  }
  #pragma unroll
  for (int i = 0; i < 4; ++i) {
    const int m = m0 + (ty << 2) + i;
    if (m >= p.M) continue;
    #pragma unroll
    for (int j = 0; j < 4; ++j) {
      const int n = n0 + (tx << 2) + j;
      if (n >= p.N) continue;
      float v = acc[i][j];
      if (p.biasMode == 1) v += bias[n];
      else if (p.biasMode == 2) v += bias[m];
      if (p.relu) v = fmaxf(v, 0.f);
      C[m * p.ldc + n] = v;
    }
  }
}

// ---------------- adj logits, s-split, partial softmax stats ----------------
// grid (8, 64): blockIdx.x = s-chunk c, blockIdx.y = z. Threads 0..195 own one s.
// pstat[(z*8+c)*32 + n] = chunk max; +16 = chunk sum.
__global__ __launch_bounds__(256) void adj_part(
    const float* __restrict__ emb, const float* __restrict__ ctx,
    float* __restrict__ Padj, float* __restrict__ pstat)
{
  __shared__ float embT[GF][16];
  __shared__ float redm[4][16];
  __shared__ float redl[4][16];
  const int c = blockIdx.x, z = blockIdx.y;
  const int g = z >> 4, b = z & 15;
  const int count = c_counts[b], off = c_offs[b];
  const float* ctxz = ctx + (size_t)z * GF * SS;
  float* Pz = Padj + (size_t)z * NMAX * SS;
  const int tid = threadIdx.x;

  #pragma unroll
  for (int n = 0; n < 16; ++n) {
    float v = 0.f;
    if (n < count) v = emb[(off + n) * INDIM + (g << 8) + tid];
    embT[tid][n] = v;
  }
  __syncthreads();

  const int s = c * SCH + tid;
  const bool act = (tid < SCH);
  float a[16] = {};
  if (act) {
    #pragma unroll 4
    for (int f = 0; f < GF; ++f) {
      const float cv = ctxz[f * SS + s];
      const float4* er = reinterpret_cast<const float4*>(&embT[f][0]);
      const float4 e0 = er[0], e1 = er[1], e2 = er[2], e3 = er[3];
      a[0]  = fmaf(e0.x, cv, a[0]);  a[1]  = fmaf(e0.y, cv, a[1]);
      a[2]  = fmaf(e0.z, cv, a[2]);  a[3]  = fmaf(e0.w, cv, a[3]);
      a[4]  = fmaf(e1.x, cv, a[4]);  a[5]  = fmaf(e1.y, cv, a[5]);
      a[6]  = fmaf(e1.z, cv, a[6]);  a[7]  = fmaf(e1.w, cv, a[7]);
      a[8]  = fmaf(e2.x, cv, a[8]);  a[9]  = fmaf(e2.y, cv, a[9]);
      a[10] = fmaf(e2.z, cv, a[10]); a[11] = fmaf(e2.w, cv, a[11]);
      a[12] = fmaf(e3.x, cv, a[12]); a[13] = fmaf(e3.y, cv, a[13]);
      a[14] = fmaf(e3.z, cv, a[14]); a[15] = fmaf(e3.w, cv, a[15]);
    }
    #pragma unroll
    for (int n = 0; n < 16; ++n) Pz[n * SS + s] = a[n];
  }

  float m[16], l[16];
  #pragma unroll
  for (int n = 0; n < 16; ++n) {
    m[n] = act ? a[n] : -3.0e38f;
    l[n] = act ? 1.0f : 0.0f;
  }
  #pragma unroll
  for (int n = 0; n < 16; ++n) {
    float mm = m[n], ll = l[n];
    #pragma unroll
    for (int d = 1; d < 64; d <<= 1) {
      const float om = __shfl_xor(mm, d, 64);
      const float ol = __shfl_xor(ll, d, 64);
      const float M = fmaxf(mm, om);
      ll = ll * __expf(mm - M) + ol * __expf(om - M);
      mm = M;
    }
    m[n] = mm; l[n] = ll;
  }
  const int wave = tid >> 6, lane = tid & 63;
  if (lane == 0) {
    #pragma unroll
    for (int n = 0; n < 16; ++n) { redm[wave][n] = m[n]; redl[wave][n] = l[n]; }
  }
  __syncthreads();
  if (tid < 16) {
    float M = -3.0e38f;
    #pragma unroll
    for (int w = 0; w < 4; ++w) M = fmaxf(M, redm[w][tid]);
    float L = 0.f;
    #pragma unroll
    for (int w = 0; w < 4; ++w) L += redl[w][tid] * __expf(redm[w][tid] - M);
    pstat[((z << 3) + c) * 32 + tid]      = M;
    pstat[((z << 3) + c) * 32 + 16 + tid] = L;
  }
  (void)count;
}

// combine 8 chunk stats -> mstat[z][0..15]=M, [16..31]=1/L. grid(4), block(256).
__global__ __launch_bounds__(256) void stat_combine(const float* __restrict__ pstat,
                                                    float* __restrict__ mstat) {
  const int idx = blockIdx.x * 256 + threadIdx.x;
  if (idx >= 64 * 16) return;
  const int z = idx >> 4, n = idx & 15;
  float M = -3.0e38f;
  #pragma unroll
  for (int cc = 0; cc < 8; ++cc) M = fmaxf(M, pstat[((z << 3) + cc) * 32 + n]);
  float L = 0.f;
  #pragma unroll
  for (int cc = 0; cc < 8; ++cc)
    L += pstat[((z << 3) + cc) * 32 + 16 + n] * __expf(pstat[((z << 3) + cc) * 32 + n] - M);
  mstat[(z << 5) + n]      = M;
  mstat[(z << 5) + 16 + n] = 1.0f / L;
}

// ---------------- upd = P @ ctx^T + emb, f-split ----------------
// grid (4, 64): blockIdx.x = f-chunk (64 features), blockIdx.y = z.
__global__ __launch_bounds__(256) void upd_part(
    const float* __restrict__ emb, const float* __restrict__ ctx,
    const float* __restrict__ Padj, const float* __restrict__ mstat,
    float* __restrict__ flat)
{
  __shared__ float Bs[32][65];
  __shared__ float Ps[32][17];
  __shared__ float sm[16], sil[16];
  const int fc = blockIdx.x, z = blockIdx.y;
  const int g = z >> 4, b = z & 15;
  const int count = c_counts[b], off = c_offs[b];
  const int f0 = fc << 6;
  const float* ctxz = ctx + (size_t)z * GF * SS;
  const float* Pz = Padj + (size_t)z * NMAX * SS;
  const int tid = threadIdx.x;
  if (tid < 16) sm[tid] = mstat[(z << 5) + tid];
  else if (tid < 32) sil[tid - 16] = mstat[(z << 5) + tid];
  __syncthreads();

  const int TX = tid & 63, TY = tid >> 6;
  float o[4] = {};
  for (int s0 = 0; s0 < SS; s0 += 32) {
    #pragma unroll
    for (int q = 0; q < 2; ++q) {
      const int idx = q * 256 + tid;
      const int ss = idx & 31, nn = idx >> 5;
      Ps[ss][nn] = __expf(Pz[nn * SS + s0 + ss] - sm[nn]) * sil[nn];
    }
    #pragma unroll
    for (int q = 0; q < 8; ++q) {
      const int idx = q * 256 + tid;
      const int ss = idx & 31, ff = idx >> 5;
      Bs[ss][ff] = ctxz[(size_t)(f0 + ff) * SS + s0 + ss];
    }
    __syncthreads();
    #pragma unroll
    for (int k = 0; k < 32; ++k) {
      const float bv = Bs[k][TX];
      #pragma unroll
      for (int i = 0; i < 4; ++i)
        o[i] = fmaf(Ps[k][(TY << 2) + i], bv, o[i]);
    }
    __syncthreads();
  }
  #pragma unroll
  for (int i = 0; i < 4; ++i) {
    const int n = (TY << 2) + i;
    if (n < count) {
      const int t = off + n;
      const int col = (g << 8) + f0 + TX;
      flat[t * INDIM + col] = o[i] + emb[t * INDIM + col];
    }
  }
}

extern "C" void kernel_launch(void* const* d_in, const int* in_sizes, int n_in,
                              void* d_out, int out_size, void* d_ws, size_t ws_size,
                              hipStream_t stream) {
  (void)in_sizes; (void)n_in; (void)out_size; (void)ws_size;
  const float* actor = (const float*)d_in[0];
  const float* fmap  = (const float*)d_in[1];
  const float* W_a   = (const float*)d_in[2];
  const float* b_a   = (const float*)d_in[3];
  const float* W_c   = (const float*)d_in[4];
  const float* b_c   = (const float*)d_in[5];
  const float* W_h   = (const float*)d_in[6];
  float* out = (float*)d_out;
  char* ws = (char*)d_ws;

  float* emb   = (float*)(ws);                     // 655,360 B
  float* flat  = (float*)(ws + 655360);            // 655,360 B
  float* mstat = (float*)(ws + 1310720);           //   8,192 B
  float* Padj  = (float*)(ws + 1318912);           // 6,422,528 B
  float* ctx   = (float*)(ws + 7741440);           // 102,760,448 B
  unsigned short* Ah  = (unsigned short*)(ws + 110501888);  // 1,769,472 B
  // pstat aliases Ah region: Ah dead after ctx_mfma, pstat born after it.
  float* pstat = (float*)(ws + 110501888);         // 65,536 B
  unsigned short* BhT = (unsigned short*)(ws + 112271360);  // 43,352,064 B

  // 0) bf16 conversions for the big GEMM
  hipLaunchKernelGGL(wc_to_bf16, dim3((4 * 256 * KPAD + 255) / 256), dim3(256), 0, stream,
                     W_c, Ah);
  hipLaunchKernelGGL(fm_to_bf16T, dim3(49, 27, 16), dim3(256), 0, stream, fmap, BhT);

  // 1) emb = actor @ W_a^T + b_a (fp32)
  {
    GemmP p{};
    p.A = actor; p.B = W_a; p.C = emb; p.bias = b_a;
    p.M = TOTAL; p.N = INDIM; p.K = INDIM;
    p.lda = INDIM; p.ldb = INDIM; p.ldc = INDIM;
    p.z2 = 1; p.biasMode = 1; p.relu = 0; p.Bt = 1;
    hipLaunchKernelGGL(gemm_f32, dim3(16, 3, 1), dim3(256), 0, stream, p);
  }
  // 2) ctx via bf16 MFMA
  hipLaunchKernelGGL(ctx_mfma, dim3(13, 2, 64), dim3(256), 0, stream, Ah, BhT, b_c, ctx);
  // 3) logits + partial stats (s-split 8)
  hipLaunchKernelGGL(adj_part, dim3(8, 64), dim3(256), 0, stream, emb, ctx, Padj, pstat);
  // 3b) combine stats
  hipLaunchKernelGGL(stat_combine, dim3(4), dim3(256), 0, stream, pstat, mstat);
  // 4) upd (f-split 4)
  hipLaunchKernelGGL(upd_part, dim3(4, 64), dim3(256), 0, stream,
                     emb, ctx, Padj, mstat, flat);
  // 5) out = relu(flat @ W_h^T) per g (fp32)
  {
    GemmP p{};
    p.A = flat; p.B = W_h; p.C = out; p.bias = flat;
    p.M = TOTAL; p.N = GF; p.K = GF;
    p.lda = INDIM; p.ldb = GF; p.ldc = INDIM;
    p.z2 = 1;
    p.sA1 = 256; p.sB1 = 65536; p.sC1 = 256;
    p.biasMode = 0; p.relu = 1; p.Bt = 1;
    hipLaunchKernelGGL(gemm_f32, dim3(4, 3, 4), dim3(256), 0, stream, p);
  }
}

// Round 4
// 447.006 us; speedup vs baseline: 5.9163x; 1.4262x over previous
//
#include <hip/hip_runtime.h>

#define TOTAL   160
#define NMAX    16
#define INDIM   1024
#define DIN     834
#define KPAD    864
#define GF      256
#define SS      1568
#define SCH     196   // s-chunk for adj_part (8 * 196 = 1568)

__constant__ int c_counts[16] = {6,14,10,8,16,12,9,11,7,13,10,10,8,12,6,8};
__constant__ int c_offs[16]   = {0,6,20,30,38,54,66,75,86,93,106,116,126,134,146,152};

using bf16x8 = __attribute__((ext_vector_type(8))) short;
using f32x4  = __attribute__((ext_vector_type(4))) float;
using us4    = __attribute__((ext_vector_type(4))) unsigned short;

__device__ inline unsigned short f2bf(float f) {
  union { float f; unsigned u; } v; v.f = f;
  const unsigned u = v.u;
  return (unsigned short)((u + 0x7FFFu + ((u >> 16) & 1u)) >> 16);
}

// ---------------- conversion / utility kernels ----------------

__global__ __launch_bounds__(256) void wc_to_bf16(const float* __restrict__ Wc,
                                                  unsigned short* __restrict__ Ah) {
  const int idx = blockIdx.x * 256 + threadIdx.x;
  if (idx >= 4 * 256 * KPAD) return;
  const int k = idx % KPAD, gm = idx / KPAD;
  Ah[idx] = (k < DIN) ? f2bf(Wc[gm * DIN + k]) : (unsigned short)0;
}

// fm [16][834][1568] fp32 -> BhT [16][1568][864] bf16 (k-contiguous, zero-padded)
__global__ __launch_bounds__(256) void fm_to_bf16T(const float* __restrict__ fm,
                                                   unsigned short* __restrict__ BhT) {
  __shared__ float tile[32][33];
  const int b  = blockIdx.z;
  const int k0 = blockIdx.y * 32;
  const int s0 = blockIdx.x * 32;
  const int tx = threadIdx.x & 31, ty = threadIdx.x >> 5;
  const float* src = fm + (size_t)b * DIN * SS;
  #pragma unroll
  for (int r = 0; r < 4; ++r) {
    const int k = k0 + ty + r * 8;
    tile[ty + r * 8][tx] = (k < DIN) ? src[(size_t)k * SS + s0 + tx] : 0.f;
  }
  __syncthreads();
  unsigned short* dst = BhT + (size_t)b * SS * KPAD;
  #pragma unroll
  for (int r = 0; r < 4; ++r) {
    const int s = s0 + ty + r * 8;
    dst[(size_t)s * KPAD + k0 + tx] = f2bf(tile[tx][ty + r * 8]);
  }
}

// packs n4 float4-groups to bf16x4
__global__ __launch_bounds__(256) void pack_bf16(const float* __restrict__ src,
                                                 unsigned short* __restrict__ dst, int n4) {
  const int i = blockIdx.x * 256 + threadIdx.x;
  if (i >= n4) return;
  const float4 v = reinterpret_cast<const float4*>(src)[i];
  us4 o; o[0] = f2bf(v.x); o[1] = f2bf(v.y); o[2] = f2bf(v.z); o[3] = f2bf(v.w);
  reinterpret_cast<us4*>(dst)[i] = o;
}

__global__ __launch_bounds__(256) void zero_emb(float* __restrict__ emb) {
  const int i = blockIdx.x * 256 + threadIdx.x;
  if (i < TOTAL * INDIM) emb[i] = 0.f;
}

// ---------------- bf16 MFMA GEMM for ctx ----------------

__global__ __launch_bounds__(256, 2) void ctx_mfma(const unsigned short* __restrict__ Ah,
                                                   const unsigned short* __restrict__ BhT,
                                                   const float* __restrict__ b_c,
                                                   float* __restrict__ ctx) {
  __shared__ unsigned short As[128 * 40];
  __shared__ unsigned short Bs[128 * 40];
  const int z = blockIdx.z, g = z >> 4, b = z & 15;
  const int n0 = blockIdx.x * 128, m0 = blockIdx.y * 128;
  const int tid = threadIdx.x;
  const int wave = tid >> 6, lane = tid & 63;
  const int wm = (wave >> 1) * 64, wn = (wave & 1) * 64;
  const int quad = lane >> 4, lr = lane & 15;

  const unsigned short* Ag = Ah + (size_t)g * 256 * KPAD + (size_t)m0 * KPAD;
  const unsigned short* Bg = BhT + (size_t)b * SS * KPAD;

  const int c0 = tid, c1 = tid + 256;
  const int r0 = c0 >> 2, ko0 = (c0 & 3) * 8;
  const int r1 = c1 >> 2, ko1 = (c1 & 3) * 8;

  f32x4 acc[4][4];
  #pragma unroll
  for (int i = 0; i < 4; ++i)
    #pragma unroll
    for (int j = 0; j < 4; ++j) acc[i][j] = (f32x4){0.f, 0.f, 0.f, 0.f};

  const uint4 zero4 = {0u, 0u, 0u, 0u};
  uint4 ra0, ra1, rb0, rb1;
  {
    ra0 = *reinterpret_cast<const uint4*>(Ag + (size_t)r0 * KPAD + ko0);
    ra1 = *reinterpret_cast<const uint4*>(Ag + (size_t)r1 * KPAD + ko1);
    rb0 = (n0 + r0 < SS) ? *reinterpret_cast<const uint4*>(Bg + (size_t)(n0 + r0) * KPAD + ko0) : zero4;
    rb1 = (n0 + r1 < SS) ? *reinterpret_cast<const uint4*>(Bg + (size_t)(n0 + r1) * KPAD + ko1) : zero4;
  }

  for (int kt = 0; kt < 27; ++kt) {
    __syncthreads();
    *reinterpret_cast<uint4*>(&As[r0 * 40 + ko0]) = ra0;
    *reinterpret_cast<uint4*>(&As[r1 * 40 + ko1]) = ra1;
    *reinterpret_cast<uint4*>(&Bs[r0 * 40 + ko0]) = rb0;
    *reinterpret_cast<uint4*>(&Bs[r1 * 40 + ko1]) = rb1;
    __syncthreads();
    if (kt < 26) {
      const int k0 = (kt + 1) * 32;
      ra0 = *reinterpret_cast<const uint4*>(Ag + (size_t)r0 * KPAD + k0 + ko0);
      ra1 = *reinterpret_cast<const uint4*>(Ag + (size_t)r1 * KPAD + k0 + ko1);
      rb0 = (n0 + r0 < SS) ? *reinterpret_cast<const uint4*>(Bg + (size_t)(n0 + r0) * KPAD + k0 + ko0) : zero4;
      rb1 = (n0 + r1 < SS) ? *reinterpret_cast<const uint4*>(Bg + (size_t)(n0 + r1) * KPAD + k0 + ko1) : zero4;
    }
    bf16x8 af[4], bfr[4];
    #pragma unroll
    for (int i = 0; i < 4; ++i)
      af[i] = *reinterpret_cast<const bf16x8*>(&As[(wm + i * 16 + lr) * 40 + quad * 8]);
    #pragma unroll
    for (int j = 0; j < 4; ++j)
      bfr[j] = *reinterpret_cast<const bf16x8*>(&Bs[(wn + j * 16 + lr) * 40 + quad * 8]);
    #pragma unroll
    for (int i = 0; i < 4; ++i)
      #pragma unroll
      for (int j = 0; j < 4; ++j)
        acc[i][j] = __builtin_amdgcn_mfma_f32_16x16x32_bf16(af[i], bfr[j], acc[i][j], 0, 0, 0);
  }

  float* Cz = ctx + (size_t)z * GF * SS;
  const float* bias = b_c + g * GF;
  #pragma unroll
  for (int i = 0; i < 4; ++i) {
    #pragma unroll
    for (int reg = 0; reg < 4; ++reg) {
      const int m = m0 + wm + i * 16 + quad * 4 + reg;
      const float bv = bias[m];
      #pragma unroll
      for (int j = 0; j < 4; ++j) {
        const int n = n0 + wn + j * 16 + lr;
        if (n < SS) Cz[(size_t)m * SS + n] = acc[i][j][reg] + bv;
      }
    }
  }
}

// ---------------- emb: fp32 split-K GEMM ----------------
// grid (16, 3, 4): n-tile, m-tile, k-chunk (256 each). C += partial via atomicAdd.
__global__ __launch_bounds__(256) void emb_splitk(const float* __restrict__ A,
                                                  const float* __restrict__ B,
                                                  const float* __restrict__ bias,
                                                  float* __restrict__ C) {
  constexpr int BM = 64, BN = 64, BK = 32;
  __shared__ float As[BK][BM + 4];
  __shared__ float Bs[BK][BN + 4];
  const int n0 = blockIdx.x * BN, m0 = blockIdx.y * BM;
  const int kbase = blockIdx.z * 256;
  const int tid = threadIdx.x;
  const int tx = tid & 15, ty = tid >> 4;
  float acc[4][4] = {};
  for (int kt = 0; kt < 8; ++kt) {
    const int k0 = kbase + kt * BK;
    #pragma unroll
    for (int q = 0; q < 8; ++q) {
      const int idx = q * 256 + tid;
      const int kk = idx & 31, mm = idx >> 5;
      const int gm = m0 + mm;
      As[kk][mm] = (gm < TOTAL) ? A[gm * INDIM + k0 + kk] : 0.f;
    }
    #pragma unroll
    for (int q = 0; q < 8; ++q) {
      const int idx = q * 256 + tid;
      const int kk = idx & 31, nn = idx >> 5;
      Bs[kk][nn] = B[(n0 + nn) * INDIM + k0 + kk];
    }
    __syncthreads();
    #pragma unroll
    for (int k = 0; k < BK; ++k) {
      const float4 av = *reinterpret_cast<const float4*>(&As[k][ty << 2]);
      const float4 bv = *reinterpret_cast<const float4*>(&Bs[k][tx << 2]);
      const float a[4] = {av.x, av.y, av.z, av.w};
      const float b[4] = {bv.x, bv.y, bv.z, bv.w};
      #pragma unroll
      for (int i = 0; i < 4; ++i)
        #pragma unroll
        for (int j = 0; j < 4; ++j)
          acc[i][j] = fmaf(a[i], b[j], acc[i][j]);
    }
    __syncthreads();
  }
  #pragma unroll
  for (int i = 0; i < 4; ++i) {
    const int m = m0 + (ty << 2) + i;
    if (m >= TOTAL) continue;
    #pragma unroll
    for (int j = 0; j < 4; ++j) {
      const int n = n0 + (tx << 2) + j;
      float v = acc[i][j];
      if (blockIdx.z == 0) v += bias[n];
      atomicAdd(&C[m * INDIM + n], v);
    }
  }
}

// ---------------- head: bf16 MFMA, out = relu(flat @ W_h^T) ----------------
// grid (4, 3, 4): n-tile(64 of 256), m-tile(64 of 160), g.
__global__ __launch_bounds__(256) void head_mfma(const unsigned short* __restrict__ flat_h,
                                                 const unsigned short* __restrict__ Wh_h,
                                                 float* __restrict__ out) {
  __shared__ unsigned short As[64 * 40];
  __shared__ unsigned short Bs[64 * 40];
  const int g = blockIdx.z;
  const int n0 = blockIdx.x * 64, m0 = blockIdx.y * 64;
  const int tid = threadIdx.x;
  const int wave = tid >> 6, lane = tid & 63;
  const int wm = (wave >> 1) * 32, wn = (wave & 1) * 32;
  const int quad = lane >> 4, lr = lane & 15;
  const int r = tid >> 2, ko = (tid & 3) * 8;

  const unsigned short* Ag = flat_h + (size_t)m0 * INDIM + g * GF;
  const unsigned short* Bg = Wh_h + (size_t)g * GF * GF + (size_t)n0 * GF;

  f32x4 acc[2][2];
  #pragma unroll
  for (int i = 0; i < 2; ++i)
    #pragma unroll
    for (int j = 0; j < 2; ++j) acc[i][j] = (f32x4){0.f, 0.f, 0.f, 0.f};

  const uint4 zero4 = {0u, 0u, 0u, 0u};
  uint4 ra, rb;
  ra = (m0 + r < TOTAL) ? *reinterpret_cast<const uint4*>(Ag + (size_t)r * INDIM + ko) : zero4;
  rb = *reinterpret_cast<const uint4*>(Bg + (size_t)r * GF + ko);

  for (int kt = 0; kt < 8; ++kt) {
    __syncthreads();
    *reinterpret_cast<uint4*>(&As[r * 40 + ko]) = ra;
    *reinterpret_cast<uint4*>(&Bs[r * 40 + ko]) = rb;
    __syncthreads();
    if (kt < 7) {
      const int k0 = (kt + 1) * 32;
      ra = (m0 + r < TOTAL) ? *reinterpret_cast<const uint4*>(Ag + (size_t)r * INDIM + k0 + ko) : zero4;
      rb = *reinterpret_cast<const uint4*>(Bg + (size_t)r * GF + k0 + ko);
    }
    bf16x8 af[2], bfr[2];
    #pragma unroll
    for (int i = 0; i < 2; ++i)
      af[i] = *reinterpret_cast<const bf16x8*>(&As[(wm + i * 16 + lr) * 40 + quad * 8]);
    #pragma unroll
    for (int j = 0; j < 2; ++j)
      bfr[j] = *reinterpret_cast<const bf16x8*>(&Bs[(wn + j * 16 + lr) * 40 + quad * 8]);
    #pragma unroll
    for (int i = 0; i < 2; ++i)
      #pragma unroll
      for (int j = 0; j < 2; ++j)
        acc[i][j] = __builtin_amdgcn_mfma_f32_16x16x32_bf16(af[i], bfr[j], acc[i][j], 0, 0, 0);
  }

  #pragma unroll
  for (int i = 0; i < 2; ++i) {
    #pragma unroll
    for (int reg = 0; reg < 4; ++reg) {
      const int m = m0 + wm + i * 16 + quad * 4 + reg;
      if (m >= TOTAL) continue;
      #pragma unroll
      for (int j = 0; j < 2; ++j) {
        const int n = n0 + wn + j * 16 + lr;
        out[(size_t)m * INDIM + g * GF + n] = fmaxf(acc[i][j][reg], 0.f);
      }
    }
  }
}

// ---------------- adj logits, s-split, partial softmax stats ----------------

__global__ __launch_bounds__(256) void adj_part(
    const float* __restrict__ emb, const float* __restrict__ ctx,
    float* __restrict__ Padj, float* __restrict__ pstat)
{
  __shared__ float embT[GF][16];
  __shared__ float redm[4][16];
  __shared__ float redl[4][16];
  const int c = blockIdx.x, z = blockIdx.y;
  const int g = z >> 4, b = z & 15;
  const int count = c_counts[b], off = c_offs[b];
  const float* ctxz = ctx + (size_t)z * GF * SS;
  float* Pz = Padj + (size_t)z * NMAX * SS;
  const int tid = threadIdx.x;

  #pragma unroll
  for (int n = 0; n < 16; ++n) {
    float v = 0.f;
    if (n < count) v = emb[(off + n) * INDIM + (g << 8) + tid];
    embT[tid][n] = v;
  }
  __syncthreads();

  const int s = c * SCH + tid;
  const bool act = (tid < SCH);
  float a[16] = {};
  if (act) {
    #pragma unroll 4
    for (int f = 0; f < GF; ++f) {
      const float cv = ctxz[f * SS + s];
      const float4* er = reinterpret_cast<const float4*>(&embT[f][0]);
      const float4 e0 = er[0], e1 = er[1], e2 = er[2], e3 = er[3];
      a[0]  = fmaf(e0.x, cv, a[0]);  a[1]  = fmaf(e0.y, cv, a[1]);
      a[2]  = fmaf(e0.z, cv, a[2]);  a[3]  = fmaf(e0.w, cv, a[3]);
      a[4]  = fmaf(e1.x, cv, a[4]);  a[5]  = fmaf(e1.y, cv, a[5]);
      a[6]  = fmaf(e1.z, cv, a[6]);  a[7]  = fmaf(e1.w, cv, a[7]);
      a[8]  = fmaf(e2.x, cv, a[8]);  a[9]  = fmaf(e2.y, cv, a[9]);
      a[10] = fmaf(e2.z, cv, a[10]); a[11] = fmaf(e2.w, cv, a[11]);
      a[12] = fmaf(e3.x, cv, a[12]); a[13] = fmaf(e3.y, cv, a[13]);
      a[14] = fmaf(e3.z, cv, a[14]); a[15] = fmaf(e3.w, cv, a[15]);
    }
    #pragma unroll
    for (int n = 0; n < 16; ++n) Pz[n * SS + s] = a[n];
  }

  float m[16], l[16];
  #pragma unroll
  for (int n = 0; n < 16; ++n) {
    m[n] = act ? a[n] : -3.0e38f;
    l[n] = act ? 1.0f : 0.0f;
  }
  #pragma unroll
  for (int n = 0; n < 16; ++n) {
    float mm = m[n], ll = l[n];
    #pragma unroll
    for (int d = 1; d < 64; d <<= 1) {
      const float om = __shfl_xor(mm, d, 64);
      const float ol = __shfl_xor(ll, d, 64);
      const float M = fmaxf(mm, om);
      ll = ll * __expf(mm - M) + ol * __expf(om - M);
      mm = M;
    }
    m[n] = mm; l[n] = ll;
  }
  const int wave = tid >> 6, lane = tid & 63;
  if (lane == 0) {
    #pragma unroll
    for (int n = 0; n < 16; ++n) { redm[wave][n] = m[n]; redl[wave][n] = l[n]; }
  }
  __syncthreads();
  if (tid < 16) {
    float M = -3.0e38f;
    #pragma unroll
    for (int w = 0; w < 4; ++w) M = fmaxf(M, redm[w][tid]);
    float L = 0.f;
    #pragma unroll
    for (int w = 0; w < 4; ++w) L += redl[w][tid] * __expf(redm[w][tid] - M);
    pstat[((z << 3) + c) * 32 + tid]      = M;
    pstat[((z << 3) + c) * 32 + 16 + tid] = L;
  }
  (void)count;
}

__global__ __launch_bounds__(256) void stat_combine(const float* __restrict__ pstat,
                                                    float* __restrict__ mstat) {
  const int idx = blockIdx.x * 256 + threadIdx.x;
  if (idx >= 64 * 16) return;
  const int z = idx >> 4, n = idx & 15;
  float M = -3.0e38f;
  #pragma unroll
  for (int cc = 0; cc < 8; ++cc) M = fmaxf(M, pstat[((z << 3) + cc) * 32 + n]);
  float L = 0.f;
  #pragma unroll
  for (int cc = 0; cc < 8; ++cc)
    L += pstat[((z << 3) + cc) * 32 + 16 + n] * __expf(pstat[((z << 3) + cc) * 32 + n] - M);
  mstat[(z << 5) + n]      = M;
  mstat[(z << 5) + 16 + n] = 1.0f / L;
}

// ---------------- upd = P @ ctx^T + emb, f-split; writes bf16 flat_h ----------------

__global__ __launch_bounds__(256) void upd_part(
    const float* __restrict__ emb, const float* __restrict__ ctx,
    const float* __restrict__ Padj, const float* __restrict__ mstat,
    unsigned short* __restrict__ flat_h)
{
  __shared__ float Bs[32][65];
  __shared__ float Ps[32][17];
  __shared__ float sm[16], sil[16];
  const int fc = blockIdx.x, z = blockIdx.y;
  const int g = z >> 4, b = z & 15;
  const int count = c_counts[b], off = c_offs[b];
  const int f0 = fc << 6;
  const float* ctxz = ctx + (size_t)z * GF * SS;
  const float* Pz = Padj + (size_t)z * NMAX * SS;
  const int tid = threadIdx.x;
  if (tid < 16) sm[tid] = mstat[(z << 5) + tid];
  else if (tid < 32) sil[tid - 16] = mstat[(z << 5) + tid];
  __syncthreads();

  const int TX = tid & 63, TY = tid >> 6;
  float o[4] = {};
  for (int s0 = 0; s0 < SS; s0 += 32) {
    #pragma unroll
    for (int q = 0; q < 2; ++q) {
      const int idx = q * 256 + tid;
      const int ss = idx & 31, nn = idx >> 5;
      Ps[ss][nn] = __expf(Pz[nn * SS + s0 + ss] - sm[nn]) * sil[nn];
    }
    #pragma unroll
    for (int q = 0; q < 8; ++q) {
      const int idx = q * 256 + tid;
      const int ss = idx & 31, ff = idx >> 5;
      Bs[ss][ff] = ctxz[(size_t)(f0 + ff) * SS + s0 + ss];
    }
    __syncthreads();
    #pragma unroll
    for (int k = 0; k < 32; ++k) {
      const float bv = Bs[k][TX];
      #pragma unroll
      for (int i = 0; i < 4; ++i)
        o[i] = fmaf(Ps[k][(TY << 2) + i], bv, o[i]);
    }
    __syncthreads();
  }
  #pragma unroll
  for (int i = 0; i < 4; ++i) {
    const int n = (TY << 2) + i;
    if (n < count) {
      const int t = off + n;
      const int col = (g << 8) + f0 + TX;
      flat_h[t * INDIM + col] = f2bf(o[i] + emb[t * INDIM + col]);
    }
  }
}

extern "C" void kernel_launch(void* const* d_in, const int* in_sizes, int n_in,
                              void* d_out, int out_size, void* d_ws, size_t ws_size,
                              hipStream_t stream) {
  (void)in_sizes; (void)n_in; (void)out_size; (void)ws_size;
  const float* actor = (const float*)d_in[0];
  const float* fmap  = (const float*)d_in[1];
  const float* W_a   = (const float*)d_in[2];
  const float* b_a   = (const float*)d_in[3];
  const float* W_c   = (const float*)d_in[4];
  const float* b_c   = (const float*)d_in[5];
  const float* W_h   = (const float*)d_in[6];
  float* out = (float*)d_out;
  char* ws = (char*)d_ws;

  float* emb            = (float*)(ws);                       // 655,360 B
  unsigned short* flat_h = (unsigned short*)(ws + 655360);    // 327,680 B (in old flat slot)
  float* mstat          = (float*)(ws + 1310720);             //   8,192 B
  float* Padj           = (float*)(ws + 1318912);             // 6,422,528 B
  float* ctx            = (float*)(ws + 7741440);             // 102,760,448 B
  unsigned short* Ah    = (unsigned short*)(ws + 110501888);  // 1,769,472 B
  float* pstat          = (float*)(ws + 110501888);           // aliases Ah (time-disjoint)
  unsigned short* BhT   = (unsigned short*)(ws + 112271360);  // 43,352,064 B
  unsigned short* Wh_h  = (unsigned short*)(ws + 155623424);  // 524,288 B

  // 0) bf16 conversions
  hipLaunchKernelGGL(wc_to_bf16, dim3((4 * 256 * KPAD + 255) / 256), dim3(256), 0, stream,
                     W_c, Ah);
  hipLaunchKernelGGL(fm_to_bf16T, dim3(49, 27, 16), dim3(256), 0, stream, fmap, BhT);
  hipLaunchKernelGGL(pack_bf16, dim3(256), dim3(256), 0, stream, W_h, Wh_h, 65536);
  hipLaunchKernelGGL(zero_emb, dim3(640), dim3(256), 0, stream, emb);

  // 1) emb = actor @ W_a^T + b_a (fp32 split-K x4, atomic accumulate)
  hipLaunchKernelGGL(emb_splitk, dim3(16, 3, 4), dim3(256), 0, stream,
                     actor, W_a, b_a, emb);

  // 2) ctx via bf16 MFMA
  hipLaunchKernelGGL(ctx_mfma, dim3(13, 2, 64), dim3(256), 0, stream, Ah, BhT, b_c, ctx);

  // 3) logits + partial stats (s-split 8)
  hipLaunchKernelGGL(adj_part, dim3(8, 64), dim3(256), 0, stream, emb, ctx, Padj, pstat);
  hipLaunchKernelGGL(stat_combine, dim3(4), dim3(256), 0, stream, pstat, mstat);

  // 4) upd (f-split 4) -> flat_h bf16
  hipLaunchKernelGGL(upd_part, dim3(4, 64), dim3(256), 0, stream,
                     emb, ctx, Padj, mstat, flat_h);

  // 5) out = relu(flat @ W_h^T) via bf16 MFMA
  hipLaunchKernelGGL(head_mfma, dim3(4, 3, 4), dim3(256), 0, stream, flat_h, Wh_h, out);
}

// Round 5
// 388.012 us; speedup vs baseline: 6.8159x; 1.1520x over previous
//
#include <hip/hip_runtime.h>

#define TOTAL   160
#define NMAX    16
#define INDIM   1024
#define DIN     834
#define KPAD    864
#define GF      256
#define SS      1568
#define SCH     196   // s-chunk for adj_part (8 * 196 = 1568)

__constant__ int c_counts[16] = {6,14,10,8,16,12,9,11,7,13,10,10,8,12,6,8};
__constant__ int c_offs[16]   = {0,6,20,30,38,54,66,75,86,93,106,116,126,134,146,152};
__constant__ int c_t0[4] = {0, 12, 24, 36};   // s-tile ranges for upd (49 tiles of 32)
__constant__ int c_t1[4] = {12, 24, 36, 49};

using bf16x8 = __attribute__((ext_vector_type(8))) short;
using f32x4  = __attribute__((ext_vector_type(4))) float;
using us4    = __attribute__((ext_vector_type(4))) unsigned short;

__device__ inline unsigned short f2bf(float f) {
  union { float f; unsigned u; } v; v.f = f;
  const unsigned u = v.u;
  return (unsigned short)((u + 0x7FFFu + ((u >> 16) & 1u)) >> 16);
}
__device__ inline float bf2f(unsigned short h) {
  union { unsigned u; float f; } v; v.u = ((unsigned)h) << 16; return v.f;
}

// ---------------- conversion / utility kernels ----------------

__global__ __launch_bounds__(256) void wc_to_bf16(const float* __restrict__ Wc,
                                                  unsigned short* __restrict__ Ah) {
  const int idx = blockIdx.x * 256 + threadIdx.x;
  if (idx >= 4 * 256 * KPAD) return;
  const int k = idx % KPAD, gm = idx / KPAD;
  Ah[idx] = (k < DIN) ? f2bf(Wc[gm * DIN + k]) : (unsigned short)0;
}

__global__ __launch_bounds__(256) void fm_to_bf16T(const float* __restrict__ fm,
                                                   unsigned short* __restrict__ BhT) {
  __shared__ float tile[32][33];
  const int b  = blockIdx.z;
  const int k0 = blockIdx.y * 32;
  const int s0 = blockIdx.x * 32;
  const int tx = threadIdx.x & 31, ty = threadIdx.x >> 5;
  const float* src = fm + (size_t)b * DIN * SS;
  #pragma unroll
  for (int r = 0; r < 4; ++r) {
    const int k = k0 + ty + r * 8;
    tile[ty + r * 8][tx] = (k < DIN) ? src[(size_t)k * SS + s0 + tx] : 0.f;
  }
  __syncthreads();
  unsigned short* dst = BhT + (size_t)b * SS * KPAD;
  #pragma unroll
  for (int r = 0; r < 4; ++r) {
    const int s = s0 + ty + r * 8;
    dst[(size_t)s * KPAD + k0 + tx] = f2bf(tile[tx][ty + r * 8]);
  }
}

__global__ __launch_bounds__(256) void pack_bf16(const float* __restrict__ src,
                                                 unsigned short* __restrict__ dst, int n4) {
  const int i = blockIdx.x * 256 + threadIdx.x;
  if (i >= n4) return;
  const float4 v = reinterpret_cast<const float4*>(src)[i];
  us4 o; o[0] = f2bf(v.x); o[1] = f2bf(v.y); o[2] = f2bf(v.z); o[3] = f2bf(v.w);
  reinterpret_cast<us4*>(dst)[i] = o;
}

__global__ __launch_bounds__(256) void zero_f32(float* __restrict__ p, int n) {
  const int i = blockIdx.x * 256 + threadIdx.x;
  if (i < n) p[i] = 0.f;
}

// flat_h = bf16(flatacc + emb)
__global__ __launch_bounds__(256) void pack_flat(const float* __restrict__ acc,
                                                 const float* __restrict__ emb,
                                                 unsigned short* __restrict__ flat_h) {
  const int i = blockIdx.x * 256 + threadIdx.x;
  if (i < TOTAL * INDIM) flat_h[i] = f2bf(acc[i] + emb[i]);
}

// ---------------- bf16 MFMA GEMM for ctx (bf16 output) ----------------

__global__ __launch_bounds__(256, 2) void ctx_mfma(const unsigned short* __restrict__ Ah,
                                                   const unsigned short* __restrict__ BhT,
                                                   const float* __restrict__ b_c,
                                                   unsigned short* __restrict__ ctx) {
  __shared__ unsigned short As[128 * 40];
  __shared__ unsigned short Bs[128 * 40];
  const int z = blockIdx.z, g = z >> 4, b = z & 15;
  const int n0 = blockIdx.x * 128, m0 = blockIdx.y * 128;
  const int tid = threadIdx.x;
  const int wave = tid >> 6, lane = tid & 63;
  const int wm = (wave >> 1) * 64, wn = (wave & 1) * 64;
  const int quad = lane >> 4, lr = lane & 15;

  const unsigned short* Ag = Ah + (size_t)g * 256 * KPAD + (size_t)m0 * KPAD;
  const unsigned short* Bg = BhT + (size_t)b * SS * KPAD;

  const int c0 = tid, c1 = tid + 256;
  const int r0 = c0 >> 2, ko0 = (c0 & 3) * 8;
  const int r1 = c1 >> 2, ko1 = (c1 & 3) * 8;

  f32x4 acc[4][4];
  #pragma unroll
  for (int i = 0; i < 4; ++i)
    #pragma unroll
    for (int j = 0; j < 4; ++j) acc[i][j] = (f32x4){0.f, 0.f, 0.f, 0.f};

  const uint4 zero4 = {0u, 0u, 0u, 0u};
  uint4 ra0, ra1, rb0, rb1;
  {
    ra0 = *reinterpret_cast<const uint4*>(Ag + (size_t)r0 * KPAD + ko0);
    ra1 = *reinterpret_cast<const uint4*>(Ag + (size_t)r1 * KPAD + ko1);
    rb0 = (n0 + r0 < SS) ? *reinterpret_cast<const uint4*>(Bg + (size_t)(n0 + r0) * KPAD + ko0) : zero4;
    rb1 = (n0 + r1 < SS) ? *reinterpret_cast<const uint4*>(Bg + (size_t)(n0 + r1) * KPAD + ko1) : zero4;
  }

  for (int kt = 0; kt < 27; ++kt) {
    __syncthreads();
    *reinterpret_cast<uint4*>(&As[r0 * 40 + ko0]) = ra0;
    *reinterpret_cast<uint4*>(&As[r1 * 40 + ko1]) = ra1;
    *reinterpret_cast<uint4*>(&Bs[r0 * 40 + ko0]) = rb0;
    *reinterpret_cast<uint4*>(&Bs[r1 * 40 + ko1]) = rb1;
    __syncthreads();
    if (kt < 26) {
      const int k0 = (kt + 1) * 32;
      ra0 = *reinterpret_cast<const uint4*>(Ag + (size_t)r0 * KPAD + k0 + ko0);
      ra1 = *reinterpret_cast<const uint4*>(Ag + (size_t)r1 * KPAD + k0 + ko1);
      rb0 = (n0 + r0 < SS) ? *reinterpret_cast<const uint4*>(Bg + (size_t)(n0 + r0) * KPAD + k0 + ko0) : zero4;
      rb1 = (n0 + r1 < SS) ? *reinterpret_cast<const uint4*>(Bg + (size_t)(n0 + r1) * KPAD + k0 + ko1) : zero4;
    }
    bf16x8 af[4], bfr[4];
    #pragma unroll
    for (int i = 0; i < 4; ++i)
      af[i] = *reinterpret_cast<const bf16x8*>(&As[(wm + i * 16 + lr) * 40 + quad * 8]);
    #pragma unroll
    for (int j = 0; j < 4; ++j)
      bfr[j] = *reinterpret_cast<const bf16x8*>(&Bs[(wn + j * 16 + lr) * 40 + quad * 8]);
    #pragma unroll
    for (int i = 0; i < 4; ++i)
      #pragma unroll
      for (int j = 0; j < 4; ++j)
        acc[i][j] = __builtin_amdgcn_mfma_f32_16x16x32_bf16(af[i], bfr[j], acc[i][j], 0, 0, 0);
  }

  unsigned short* Cz = ctx + (size_t)z * GF * SS;
  const float* bias = b_c + g * GF;
  #pragma unroll
  for (int i = 0; i < 4; ++i) {
    #pragma unroll
    for (int reg = 0; reg < 4; ++reg) {
      const int m = m0 + wm + i * 16 + quad * 4 + reg;
      const float bv = bias[m];
      #pragma unroll
      for (int j = 0; j < 4; ++j) {
        const int n = n0 + wn + j * 16 + lr;
        if (n < SS) Cz[(size_t)m * SS + n] = f2bf(acc[i][j][reg] + bv);
      }
    }
  }
}

// ---------------- emb: fp32 split-K GEMM ----------------

__global__ __launch_bounds__(256) void emb_splitk(const float* __restrict__ A,
                                                  const float* __restrict__ B,
                                                  const float* __restrict__ bias,
                                                  float* __restrict__ C) {
  constexpr int BM = 64, BN = 64, BK = 32;
  __shared__ float As[BK][BM + 4];
  __shared__ float Bs[BK][BN + 4];
  const int n0 = blockIdx.x * BN, m0 = blockIdx.y * BM;
  const int kbase = blockIdx.z * 256;
  const int tid = threadIdx.x;
  const int tx = tid & 15, ty = tid >> 4;
  float acc[4][4] = {};
  for (int kt = 0; kt < 8; ++kt) {
    const int k0 = kbase + kt * BK;
    #pragma unroll
    for (int q = 0; q < 8; ++q) {
      const int idx = q * 256 + tid;
      const int kk = idx & 31, mm = idx >> 5;
      const int gm = m0 + mm;
      As[kk][mm] = (gm < TOTAL) ? A[gm * INDIM + k0 + kk] : 0.f;
    }
    #pragma unroll
    for (int q = 0; q < 8; ++q) {
      const int idx = q * 256 + tid;
      const int kk = idx & 31, nn = idx >> 5;
      Bs[kk][nn] = B[(n0 + nn) * INDIM + k0 + kk];
    }
    __syncthreads();
    #pragma unroll
    for (int k = 0; k < BK; ++k) {
      const float4 av = *reinterpret_cast<const float4*>(&As[k][ty << 2]);
      const float4 bv = *reinterpret_cast<const float4*>(&Bs[k][tx << 2]);
      const float a[4] = {av.x, av.y, av.z, av.w};
      const float b[4] = {bv.x, bv.y, bv.z, bv.w};
      #pragma unroll
      for (int i = 0; i < 4; ++i)
        #pragma unroll
        for (int j = 0; j < 4; ++j)
          acc[i][j] = fmaf(a[i], b[j], acc[i][j]);
    }
    __syncthreads();
  }
  #pragma unroll
  for (int i = 0; i < 4; ++i) {
    const int m = m0 + (ty << 2) + i;
    if (m >= TOTAL) continue;
    #pragma unroll
    for (int j = 0; j < 4; ++j) {
      const int n = n0 + (tx << 2) + j;
      float v = acc[i][j];
      if (blockIdx.z == 0) v += bias[n];
      atomicAdd(&C[m * INDIM + n], v);
    }
  }
}

// ---------------- head: bf16 MFMA, out = relu(flat @ W_h^T) ----------------

__global__ __launch_bounds__(256) void head_mfma(const unsigned short* __restrict__ flat_h,
                                                 const unsigned short* __restrict__ Wh_h,
                                                 float* __restrict__ out) {
  __shared__ unsigned short As[64 * 40];
  __shared__ unsigned short Bs[64 * 40];
  const int g = blockIdx.z;
  const int n0 = blockIdx.x * 64, m0 = blockIdx.y * 64;
  const int tid = threadIdx.x;
  const int wave = tid >> 6, lane = tid & 63;
  const int wm = (wave >> 1) * 32, wn = (wave & 1) * 32;
  const int quad = lane >> 4, lr = lane & 15;
  const int r = tid >> 2, ko = (tid & 3) * 8;

  const unsigned short* Ag = flat_h + (size_t)m0 * INDIM + g * GF;
  const unsigned short* Bg = Wh_h + (size_t)g * GF * GF + (size_t)n0 * GF;

  f32x4 acc[2][2];
  #pragma unroll
  for (int i = 0; i < 2; ++i)
    #pragma unroll
    for (int j = 0; j < 2; ++j) acc[i][j] = (f32x4){0.f, 0.f, 0.f, 0.f};

  const uint4 zero4 = {0u, 0u, 0u, 0u};
  uint4 ra, rb;
  ra = (m0 + r < TOTAL) ? *reinterpret_cast<const uint4*>(Ag + (size_t)r * INDIM + ko) : zero4;
  rb = *reinterpret_cast<const uint4*>(Bg + (size_t)r * GF + ko);

  for (int kt = 0; kt < 8; ++kt) {
    __syncthreads();
    *reinterpret_cast<uint4*>(&As[r * 40 + ko]) = ra;
    *reinterpret_cast<uint4*>(&Bs[r * 40 + ko]) = rb;
    __syncthreads();
    if (kt < 7) {
      const int k0 = (kt + 1) * 32;
      ra = (m0 + r < TOTAL) ? *reinterpret_cast<const uint4*>(Ag + (size_t)r * INDIM + k0 + ko) : zero4;
      rb = *reinterpret_cast<const uint4*>(Bg + (size_t)r * GF + k0 + ko);
    }
    bf16x8 af[2], bfr[2];
    #pragma unroll
    for (int i = 0; i < 2; ++i)
      af[i] = *reinterpret_cast<const bf16x8*>(&As[(wm + i * 16 + lr) * 40 + quad * 8]);
    #pragma unroll
    for (int j = 0; j < 2; ++j)
      bfr[j] = *reinterpret_cast<const bf16x8*>(&Bs[(wn + j * 16 + lr) * 40 + quad * 8]);
    #pragma unroll
    for (int i = 0; i < 2; ++i)
      #pragma unroll
      for (int j = 0; j < 2; ++j)
        acc[i][j] = __builtin_amdgcn_mfma_f32_16x16x32_bf16(af[i], bfr[j], acc[i][j], 0, 0, 0);
  }

  #pragma unroll
  for (int i = 0; i < 2; ++i) {
    #pragma unroll
    for (int reg = 0; reg < 4; ++reg) {
      const int m = m0 + wm + i * 16 + quad * 4 + reg;
      if (m >= TOTAL) continue;
      #pragma unroll
      for (int j = 0; j < 2; ++j) {
        const int n = n0 + wn + j * 16 + lr;
        out[(size_t)m * INDIM + g * GF + n] = fmaxf(acc[i][j][reg], 0.f);
      }
    }
  }
}

// ---------------- adj logits (bf16 ctx), s-split, partial stats ----------------

__global__ __launch_bounds__(256) void adj_part(
    const float* __restrict__ emb, const unsigned short* __restrict__ ctx,
    float* __restrict__ Padj, float* __restrict__ pstat)
{
  __shared__ float embT[GF][16];
  __shared__ float redm[4][16];
  __shared__ float redl[4][16];
  const int c = blockIdx.x, z = blockIdx.y;
  const int g = z >> 4, b = z & 15;
  const int count = c_counts[b], off = c_offs[b];
  const unsigned short* ctxz = ctx + (size_t)z * GF * SS;
  float* Pz = Padj + (size_t)z * NMAX * SS;
  const int tid = threadIdx.x;

  #pragma unroll
  for (int n = 0; n < 16; ++n) {
    float v = 0.f;
    if (n < count) v = emb[(off + n) * INDIM + (g << 8) + tid];
    embT[tid][n] = v;
  }
  __syncthreads();

  const int s = c * SCH + tid;
  const bool act = (tid < SCH);
  float a[16] = {};
  if (act) {
    #pragma unroll 4
    for (int f = 0; f < GF; ++f) {
      const float cv = bf2f(ctxz[f * SS + s]);
      const float4* er = reinterpret_cast<const float4*>(&embT[f][0]);
      const float4 e0 = er[0], e1 = er[1], e2 = er[2], e3 = er[3];
      a[0]  = fmaf(e0.x, cv, a[0]);  a[1]  = fmaf(e0.y, cv, a[1]);
      a[2]  = fmaf(e0.z, cv, a[2]);  a[3]  = fmaf(e0.w, cv, a[3]);
      a[4]  = fmaf(e1.x, cv, a[4]);  a[5]  = fmaf(e1.y, cv, a[5]);
      a[6]  = fmaf(e1.z, cv, a[6]);  a[7]  = fmaf(e1.w, cv, a[7]);
      a[8]  = fmaf(e2.x, cv, a[8]);  a[9]  = fmaf(e2.y, cv, a[9]);
      a[10] = fmaf(e2.z, cv, a[10]); a[11] = fmaf(e2.w, cv, a[11]);
      a[12] = fmaf(e3.x, cv, a[12]); a[13] = fmaf(e3.y, cv, a[13]);
      a[14] = fmaf(e3.z, cv, a[14]); a[15] = fmaf(e3.w, cv, a[15]);
    }
    #pragma unroll
    for (int n = 0; n < 16; ++n) Pz[n * SS + s] = a[n];
  }

  float m[16], l[16];
  #pragma unroll
  for (int n = 0; n < 16; ++n) {
    m[n] = act ? a[n] : -3.0e38f;
    l[n] = act ? 1.0f : 0.0f;
  }
  #pragma unroll
  for (int n = 0; n < 16; ++n) {
    float mm = m[n], ll = l[n];
    #pragma unroll
    for (int d = 1; d < 64; d <<= 1) {
      const float om = __shfl_xor(mm, d, 64);
      const float ol = __shfl_xor(ll, d, 64);
      const float M = fmaxf(mm, om);
      ll = ll * __expf(mm - M) + ol * __expf(om - M);
      mm = M;
    }
    m[n] = mm; l[n] = ll;
  }
  const int wave = tid >> 6, lane = tid & 63;
  if (lane == 0) {
    #pragma unroll
    for (int n = 0; n < 16; ++n) { redm[wave][n] = m[n]; redl[wave][n] = l[n]; }
  }
  __syncthreads();
  if (tid < 16) {
    float M = -3.0e38f;
    #pragma unroll
    for (int w = 0; w < 4; ++w) M = fmaxf(M, redm[w][tid]);
    float L = 0.f;
    #pragma unroll
    for (int w = 0; w < 4; ++w) L += redl[w][tid] * __expf(redm[w][tid] - M);
    pstat[((z << 3) + c) * 32 + tid]      = M;
    pstat[((z << 3) + c) * 32 + 16 + tid] = L;
  }
  (void)count;
}

__global__ __launch_bounds__(256) void stat_combine(const float* __restrict__ pstat,
                                                    float* __restrict__ mstat) {
  const int idx = blockIdx.x * 256 + threadIdx.x;
  if (idx >= 64 * 16) return;
  const int z = idx >> 4, n = idx & 15;
  float M = -3.0e38f;
  #pragma unroll
  for (int cc = 0; cc < 8; ++cc) M = fmaxf(M, pstat[((z << 3) + cc) * 32 + n]);
  float L = 0.f;
  #pragma unroll
  for (int cc = 0; cc < 8; ++cc)
    L += pstat[((z << 3) + cc) * 32 + 16 + n] * __expf(pstat[((z << 3) + cc) * 32 + n] - M);
  mstat[(z << 5) + n]      = M;
  mstat[(z << 5) + 16 + n] = 1.0f / L;
}

// ---------------- upd: f-split x s-split, atomic partial O ----------------
// grid (4 fc, 4 sc, 64 z). O[n][f] partial over s-tiles [c_t0[sc], c_t1[sc]).
__global__ __launch_bounds__(256) void upd_part(
    const unsigned short* __restrict__ ctx, const float* __restrict__ Padj,
    const float* __restrict__ mstat, float* __restrict__ flatacc)
{
  __shared__ float Bs[32][65];
  __shared__ float Ps[32][17];
  __shared__ float sm[16], sil[16];
  const int fc = blockIdx.x, sc = blockIdx.y, z = blockIdx.z;
  const int g = z >> 4, b = z & 15;
  const int count = c_counts[b], off = c_offs[b];
  const int f0 = fc << 6;
  const int t0 = c_t0[sc], t1 = c_t1[sc];
  const unsigned short* ctxz = ctx + (size_t)z * GF * SS;
  const float* Pz = Padj + (size_t)z * NMAX * SS;
  const int tid = threadIdx.x;
  if (tid < 16) sm[tid] = mstat[(z << 5) + tid];
  else if (tid < 32) sil[tid - 16] = mstat[(z << 5) + tid];
  __syncthreads();

  const int TX = tid & 63, TY = tid >> 6;
  float o[4] = {};
  for (int t = t0; t < t1; ++t) {
    const int s0 = t * 32;
    #pragma unroll
    for (int q = 0; q < 2; ++q) {
      const int idx = q * 256 + tid;
      const int ss = idx & 31, nn = idx >> 5;
      Ps[ss][nn] = __expf(Pz[nn * SS + s0 + ss] - sm[nn]) * sil[nn];
    }
    // stage ctx bf16 -> fp32 LDS: 64 f x 32 s, ushort2 per load
    #pragma unroll
    for (int q = 0; q < 4; ++q) {
      const int idx = q * 256 + tid;
      const int sp = idx & 15, ff = idx >> 4;
      const unsigned pair = *reinterpret_cast<const unsigned*>(
          &ctxz[(size_t)(f0 + ff) * SS + s0 + sp * 2]);
      Bs[sp * 2][ff]     = bf2f((unsigned short)(pair & 0xFFFF));
      Bs[sp * 2 + 1][ff] = bf2f((unsigned short)(pair >> 16));
    }
    __syncthreads();
    #pragma unroll
    for (int k = 0; k < 32; ++k) {
      const float bv = Bs[k][TX];
      #pragma unroll
      for (int i = 0; i < 4; ++i)
        o[i] = fmaf(Ps[k][(TY << 2) + i], bv, o[i]);
    }
    __syncthreads();
  }
  #pragma unroll
  for (int i = 0; i < 4; ++i) {
    const int n = (TY << 2) + i;
    if (n < count) {
      const int t = off + n;
      const int col = (g << 8) + f0 + TX;
      atomicAdd(&flatacc[t * INDIM + col], o[i]);
    }
  }
}

extern "C" void kernel_launch(void* const* d_in, const int* in_sizes, int n_in,
                              void* d_out, int out_size, void* d_ws, size_t ws_size,
                              hipStream_t stream) {
  (void)in_sizes; (void)n_in; (void)out_size; (void)ws_size;
  const float* actor = (const float*)d_in[0];
  const float* fmap  = (const float*)d_in[1];
  const float* W_a   = (const float*)d_in[2];
  const float* b_a   = (const float*)d_in[3];
  const float* W_c   = (const float*)d_in[4];
  const float* b_c   = (const float*)d_in[5];
  const float* W_h   = (const float*)d_in[6];
  float* out = (float*)d_out;
  char* ws = (char*)d_ws;

  float* emb             = (float*)(ws);                        // 655,360 B
  float* flatacc         = (float*)(ws + 655360);               // 655,360 B
  unsigned short* flat_h = (unsigned short*)(ws + 1310720);     // 327,680 B
  float* mstat           = (float*)(ws + 1638400);              //   8,192 B
  float* Padj            = (float*)(ws + 1646592);              // 6,422,528 B
  unsigned short* ctx    = (unsigned short*)(ws + 8069120);     // 51,380,224 B (bf16)
  unsigned short* Ah     = (unsigned short*)(ws + 59449344);    // 1,769,472 B
  float* pstat           = (float*)(ws + 59449344);             // aliases Ah (time-disjoint)
  unsigned short* BhT    = (unsigned short*)(ws + 61218816);    // 43,352,064 B
  unsigned short* Wh_h   = (unsigned short*)(ws + 104570880);   // 524,288 B

  // 0) conversions + zeroing
  hipLaunchKernelGGL(wc_to_bf16, dim3((4 * 256 * KPAD + 255) / 256), dim3(256), 0, stream,
                     W_c, Ah);
  hipLaunchKernelGGL(fm_to_bf16T, dim3(49, 27, 16), dim3(256), 0, stream, fmap, BhT);
  hipLaunchKernelGGL(pack_bf16, dim3(256), dim3(256), 0, stream, W_h, Wh_h, 65536);
  hipLaunchKernelGGL(zero_f32, dim3(640), dim3(256), 0, stream, emb, TOTAL * INDIM);
  hipLaunchKernelGGL(zero_f32, dim3(640), dim3(256), 0, stream, flatacc, TOTAL * INDIM);

  // 1) emb = actor @ W_a^T + b_a (fp32 split-K x4, atomic accumulate)
  hipLaunchKernelGGL(emb_splitk, dim3(16, 3, 4), dim3(256), 0, stream,
                     actor, W_a, b_a, emb);

  // 2) ctx via bf16 MFMA (bf16 output)
  hipLaunchKernelGGL(ctx_mfma, dim3(13, 2, 64), dim3(256), 0, stream, Ah, BhT, b_c, ctx);

  // 3) logits + partial stats (s-split 8)
  hipLaunchKernelGGL(adj_part, dim3(8, 64), dim3(256), 0, stream, emb, ctx, Padj, pstat);
  hipLaunchKernelGGL(stat_combine, dim3(4), dim3(256), 0, stream, pstat, mstat);

  // 4) upd (f-split 4 x s-split 4) -> atomic partial O in flatacc
  hipLaunchKernelGGL(upd_part, dim3(4, 4, 64), dim3(256), 0, stream,
                     ctx, Padj, mstat, flatacc);

  // 4b) flat_h = bf16(flatacc + emb)
  hipLaunchKernelGGL(pack_flat, dim3(640), dim3(256), 0, stream, flatacc, emb, flat_h);

  // 5) out = relu(flat @ W_h^T) via bf16 MFMA
  hipLaunchKernelGGL(head_mfma, dim3(4, 3, 4), dim3(256), 0, stream, flat_h, Wh_h, out);
}

// Round 6
// 347.435 us; speedup vs baseline: 7.6119x; 1.1168x over previous
//
#include <hip/hip_runtime.h>

#define TOTAL   160
#define NMAX    16
#define INDIM   1024
#define DIN     834
#define KPAD    864
#define GF      256
#define SS      1568
#define SPAD    1664   // 13 * 128

__constant__ int c_counts[16] = {6,14,10,8,16,12,9,11,7,13,10,10,8,12,6,8};
__constant__ int c_offs[16]   = {0,6,20,30,38,54,66,75,86,93,106,116,126,134,146,152};
__constant__ int c_t0[4] = {0, 12, 24, 36};   // s-tile ranges for upd (49 tiles of 32)
__constant__ int c_t1[4] = {12, 24, 36, 49};

using bf16x8 = __attribute__((ext_vector_type(8))) short;
using f32x4  = __attribute__((ext_vector_type(4))) float;
using us4    = __attribute__((ext_vector_type(4))) unsigned short;

__device__ inline unsigned short f2bf(float f) {
  union { float f; unsigned u; } v; v.f = f;
  const unsigned u = v.u;
  return (unsigned short)((u + 0x7FFFu + ((u >> 16) & 1u)) >> 16);
}
__device__ inline float bf2f(unsigned short h) {
  union { unsigned u; float f; } v; v.u = ((unsigned)h) << 16; return v.f;
}

// ---------------- conversion / utility kernels ----------------

__global__ __launch_bounds__(256) void wc_to_bf16(const float* __restrict__ Wc,
                                                  unsigned short* __restrict__ Ah) {
  const int idx = blockIdx.x * 256 + threadIdx.x;
  if (idx >= 4 * 256 * KPAD) return;
  const int k = idx % KPAD, gm = idx / KPAD;
  Ah[idx] = (k < DIN) ? f2bf(Wc[gm * DIN + k]) : (unsigned short)0;
}

// fm [16][834][1568] fp32 -> BhT [16][1568][864] bf16 (k-contiguous, zero-padded)
__global__ __launch_bounds__(256) void fm_to_bf16T(const float* __restrict__ fm,
                                                   unsigned short* __restrict__ BhT) {
  __shared__ float tile[32][33];
  const int b  = blockIdx.z;
  const int k0 = blockIdx.y * 32;
  const int s0 = blockIdx.x * 32;
  const int tx = threadIdx.x & 31, ty = threadIdx.x >> 5;
  const float* src = fm + (size_t)b * DIN * SS;
  #pragma unroll
  for (int r = 0; r < 4; ++r) {
    const int k = k0 + ty + r * 8;
    tile[ty + r * 8][tx] = (k < DIN) ? src[(size_t)k * SS + s0 + tx] : 0.f;
  }
  __syncthreads();
  unsigned short* dst = BhT + (size_t)b * SS * KPAD;
  #pragma unroll
  for (int r = 0; r < 4; ++r) {
    const int s = s0 + ty + r * 8;
    dst[(size_t)s * KPAD + k0 + tx] = f2bf(tile[tx][ty + r * 8]);
  }
}

__global__ __launch_bounds__(256) void pack_bf16(const float* __restrict__ src,
                                                 unsigned short* __restrict__ dst, int n4) {
  const int i = blockIdx.x * 256 + threadIdx.x;
  if (i >= n4) return;
  const float4 v = reinterpret_cast<const float4*>(src)[i];
  us4 o; o[0] = f2bf(v.x); o[1] = f2bf(v.y); o[2] = f2bf(v.z); o[3] = f2bf(v.w);
  reinterpret_cast<us4*>(dst)[i] = o;
}

__global__ __launch_bounds__(256) void zero_f32(float* __restrict__ p, int n) {
  const int i = blockIdx.x * 256 + threadIdx.x;
  if (i < n) p[i] = 0.f;
}

// flat_h = bf16(flatacc + emb)
__global__ __launch_bounds__(256) void pack_flat(const float* __restrict__ acc,
                                                 const float* __restrict__ emb,
                                                 unsigned short* __restrict__ flat_h) {
  const int i = blockIdx.x * 256 + threadIdx.x;
  if (i < TOTAL * INDIM) flat_h[i] = f2bf(acc[i] + emb[i]);
}

// ---------------- ctx GEMM (operands swapped): ctxT[z][s][f] bf16 ----------------
// D[m=s][n=f] = sum_k fmT[b][s][k] * Wc[g][f][k] + b_c[g][f]
__global__ __launch_bounds__(256, 2) void ctx_mfma(const unsigned short* __restrict__ Ah,
                                                   const unsigned short* __restrict__ BhT,
                                                   const float* __restrict__ b_c,
                                                   unsigned short* __restrict__ ctxT) {
  __shared__ unsigned short As[128 * 40];   // s rows
  __shared__ unsigned short Bs[128 * 40];   // f rows
  const int z = blockIdx.z, g = z >> 4, b = z & 15;
  const int n0 = blockIdx.x * 128;          // f
  const int m0 = blockIdx.y * 128;          // s
  const int tid = threadIdx.x;
  const int wave = tid >> 6, lane = tid & 63;
  const int wm = (wave >> 1) * 64, wn = (wave & 1) * 64;
  const int quad = lane >> 4, lr = lane & 15;

  const unsigned short* Ag = BhT + (size_t)b * SS * KPAD;                    // rows s (guard)
  const unsigned short* Bg = Ah + (size_t)g * 256 * KPAD + (size_t)n0 * KPAD; // rows f (valid)

  const int c0 = tid, c1 = tid + 256;
  const int r0 = c0 >> 2, ko0 = (c0 & 3) * 8;
  const int r1 = c1 >> 2, ko1 = (c1 & 3) * 8;

  f32x4 acc[4][4];
  #pragma unroll
  for (int i = 0; i < 4; ++i)
    #pragma unroll
    for (int j = 0; j < 4; ++j) acc[i][j] = (f32x4){0.f, 0.f, 0.f, 0.f};

  const uint4 zero4 = {0u, 0u, 0u, 0u};
  uint4 ra0, ra1, rb0, rb1;
  {
    ra0 = (m0 + r0 < SS) ? *reinterpret_cast<const uint4*>(Ag + (size_t)(m0 + r0) * KPAD + ko0) : zero4;
    ra1 = (m0 + r1 < SS) ? *reinterpret_cast<const uint4*>(Ag + (size_t)(m0 + r1) * KPAD + ko1) : zero4;
    rb0 = *reinterpret_cast<const uint4*>(Bg + (size_t)r0 * KPAD + ko0);
    rb1 = *reinterpret_cast<const uint4*>(Bg + (size_t)r1 * KPAD + ko1);
  }

  for (int kt = 0; kt < 27; ++kt) {
    __syncthreads();
    *reinterpret_cast<uint4*>(&As[r0 * 40 + ko0]) = ra0;
    *reinterpret_cast<uint4*>(&As[r1 * 40 + ko1]) = ra1;
    *reinterpret_cast<uint4*>(&Bs[r0 * 40 + ko0]) = rb0;
    *reinterpret_cast<uint4*>(&Bs[r1 * 40 + ko1]) = rb1;
    __syncthreads();
    if (kt < 26) {
      const int k0 = (kt + 1) * 32;
      ra0 = (m0 + r0 < SS) ? *reinterpret_cast<const uint4*>(Ag + (size_t)(m0 + r0) * KPAD + k0 + ko0) : zero4;
      ra1 = (m0 + r1 < SS) ? *reinterpret_cast<const uint4*>(Ag + (size_t)(m0 + r1) * KPAD + k0 + ko1) : zero4;
      rb0 = *reinterpret_cast<const uint4*>(Bg + (size_t)r0 * KPAD + k0 + ko0);
      rb1 = *reinterpret_cast<const uint4*>(Bg + (size_t)r1 * KPAD + k0 + ko1);
    }
    bf16x8 af[4], bfr[4];
    #pragma unroll
    for (int i = 0; i < 4; ++i)
      af[i] = *reinterpret_cast<const bf16x8*>(&As[(wm + i * 16 + lr) * 40 + quad * 8]);
    #pragma unroll
    for (int j = 0; j < 4; ++j)
      bfr[j] = *reinterpret_cast<const bf16x8*>(&Bs[(wn + j * 16 + lr) * 40 + quad * 8]);
    #pragma unroll
    for (int i = 0; i < 4; ++i)
      #pragma unroll
      for (int j = 0; j < 4; ++j)
        acc[i][j] = __builtin_amdgcn_mfma_f32_16x16x32_bf16(af[i], bfr[j], acc[i][j], 0, 0, 0);
  }

  unsigned short* Cz = ctxT + (size_t)z * SPAD * GF;
  const float* bias = b_c + g * GF;
  #pragma unroll
  for (int j = 0; j < 4; ++j) {
    const int n = n0 + wn + j * 16 + lr;
    const float bv = bias[n];
    #pragma unroll
    for (int i = 0; i < 4; ++i) {
      #pragma unroll
      for (int reg = 0; reg < 4; ++reg) {
        const int m = m0 + wm + i * 16 + quad * 4 + reg;   // s row < SPAD always
        Cz[(size_t)m * GF + n] = f2bf(acc[i][j][reg] + bv);
      }
    }
  }
}

// ---------------- emb: fp32 split-K GEMM ----------------

__global__ __launch_bounds__(256) void emb_splitk(const float* __restrict__ A,
                                                  const float* __restrict__ B,
                                                  const float* __restrict__ bias,
                                                  float* __restrict__ C) {
  constexpr int BM = 64, BN = 64, BK = 32;
  __shared__ float As[BK][BM + 4];
  __shared__ float Bs[BK][BN + 4];
  const int n0 = blockIdx.x * BN, m0 = blockIdx.y * BM;
  const int kbase = blockIdx.z * 256;
  const int tid = threadIdx.x;
  const int tx = tid & 15, ty = tid >> 4;
  float acc[4][4] = {};
  for (int kt = 0; kt < 8; ++kt) {
    const int k0 = kbase + kt * BK;
    #pragma unroll
    for (int q = 0; q < 8; ++q) {
      const int idx = q * 256 + tid;
      const int kk = idx & 31, mm = idx >> 5;
      const int gm = m0 + mm;
      As[kk][mm] = (gm < TOTAL) ? A[gm * INDIM + k0 + kk] : 0.f;
    }
    #pragma unroll
    for (int q = 0; q < 8; ++q) {
      const int idx = q * 256 + tid;
      const int kk = idx & 31, nn = idx >> 5;
      Bs[kk][nn] = B[(n0 + nn) * INDIM + k0 + kk];
    }
    __syncthreads();
    #pragma unroll
    for (int k = 0; k < BK; ++k) {
      const float4 av = *reinterpret_cast<const float4*>(&As[k][ty << 2]);
      const float4 bv = *reinterpret_cast<const float4*>(&Bs[k][tx << 2]);
      const float a[4] = {av.x, av.y, av.z, av.w};
      const float b[4] = {bv.x, bv.y, bv.z, bv.w};
      #pragma unroll
      for (int i = 0; i < 4; ++i)
        #pragma unroll
        for (int j = 0; j < 4; ++j)
          acc[i][j] = fmaf(a[i], b[j], acc[i][j]);
    }
    __syncthreads();
  }
  #pragma unroll
  for (int i = 0; i < 4; ++i) {
    const int m = m0 + (ty << 2) + i;
    if (m >= TOTAL) continue;
    #pragma unroll
    for (int j = 0; j < 4; ++j) {
      const int n = n0 + (tx << 2) + j;
      float v = acc[i][j];
      if (blockIdx.z == 0) v += bias[n];
      atomicAdd(&C[m * INDIM + n], v);
    }
  }
}

// ---------------- head: bf16 MFMA, out = relu(flat @ W_h^T) ----------------

__global__ __launch_bounds__(256) void head_mfma(const unsigned short* __restrict__ flat_h,
                                                 const unsigned short* __restrict__ Wh_h,
                                                 float* __restrict__ out) {
  __shared__ unsigned short As[64 * 40];
  __shared__ unsigned short Bs[64 * 40];
  const int g = blockIdx.z;
  const int n0 = blockIdx.x * 64, m0 = blockIdx.y * 64;
  const int tid = threadIdx.x;
  const int wave = tid >> 6, lane = tid & 63;
  const int wm = (wave >> 1) * 32, wn = (wave & 1) * 32;
  const int quad = lane >> 4, lr = lane & 15;
  const int r = tid >> 2, ko = (tid & 3) * 8;

  const unsigned short* Ag = flat_h + (size_t)m0 * INDIM + g * GF;
  const unsigned short* Bg = Wh_h + (size_t)g * GF * GF + (size_t)n0 * GF;

  f32x4 acc[2][2];
  #pragma unroll
  for (int i = 0; i < 2; ++i)
    #pragma unroll
    for (int j = 0; j < 2; ++j) acc[i][j] = (f32x4){0.f, 0.f, 0.f, 0.f};

  const uint4 zero4 = {0u, 0u, 0u, 0u};
  uint4 ra, rb;
  ra = (m0 + r < TOTAL) ? *reinterpret_cast<const uint4*>(Ag + (size_t)r * INDIM + ko) : zero4;
  rb = *reinterpret_cast<const uint4*>(Bg + (size_t)r * GF + ko);

  for (int kt = 0; kt < 8; ++kt) {
    __syncthreads();
    *reinterpret_cast<uint4*>(&As[r * 40 + ko]) = ra;
    *reinterpret_cast<uint4*>(&Bs[r * 40 + ko]) = rb;
    __syncthreads();
    if (kt < 7) {
      const int k0 = (kt + 1) * 32;
      ra = (m0 + r < TOTAL) ? *reinterpret_cast<const uint4*>(Ag + (size_t)r * INDIM + k0 + ko) : zero4;
      rb = *reinterpret_cast<const uint4*>(Bg + (size_t)r * GF + k0 + ko);
    }
    bf16x8 af[2], bfr[2];
    #pragma unroll
    for (int i = 0; i < 2; ++i)
      af[i] = *reinterpret_cast<const bf16x8*>(&As[(wm + i * 16 + lr) * 40 + quad * 8]);
    #pragma unroll
    for (int j = 0; j < 2; ++j)
      bfr[j] = *reinterpret_cast<const bf16x8*>(&Bs[(wn + j * 16 + lr) * 40 + quad * 8]);
    #pragma unroll
    for (int i = 0; i < 2; ++i)
      #pragma unroll
      for (int j = 0; j < 2; ++j)
        acc[i][j] = __builtin_amdgcn_mfma_f32_16x16x32_bf16(af[i], bfr[j], acc[i][j], 0, 0, 0);
  }

  #pragma unroll
  for (int i = 0; i < 2; ++i) {
    #pragma unroll
    for (int reg = 0; reg < 4; ++reg) {
      const int m = m0 + wm + i * 16 + quad * 4 + reg;
      if (m >= TOTAL) continue;
      #pragma unroll
      for (int j = 0; j < 2; ++j) {
        const int n = n0 + wn + j * 16 + lr;
        out[(size_t)m * INDIM + g * GF + n] = fmaxf(acc[i][j][reg], 0.f);
      }
    }
  }
}

// ---------------- adj via MFMA: PT[z][s][n] = logits^T, partial stats ----------------
// grid (13, 64), block 256 (4 waves x 32 s each). A = ctxT (global direct), B = emb_h.
__global__ __launch_bounds__(256) void adj_mfma(const unsigned short* __restrict__ ctxT,
                                                const unsigned short* __restrict__ emb_h,
                                                float* __restrict__ PT,
                                                float* __restrict__ pstat) {
  __shared__ float redm[4][16];
  __shared__ float redl[4][16];
  const int blk = blockIdx.x, z = blockIdx.y;
  const int g = z >> 4, b = z & 15;
  const int count = c_counts[b], off = c_offs[b];
  const int tid = threadIdx.x, wave = tid >> 6, lane = tid & 63;
  const int quad = lane >> 4, lr = lane & 15;
  const int sbase = blk * 128 + wave * 32;
  const unsigned short* Az = ctxT + (size_t)z * SPAD * GF;
  const bool bvalid = (lr < count);
  const unsigned short* Brow = emb_h + (size_t)(off + (bvalid ? lr : 0)) * INDIM + (g << 8);

  f32x4 acc[2] = {(f32x4){0.f, 0.f, 0.f, 0.f}, (f32x4){0.f, 0.f, 0.f, 0.f}};
  const bf16x8 zero8 = (bf16x8)(short)0;

  #pragma unroll
  for (int kk = 0; kk < 8; ++kk) {
    const int f = kk * 32 + quad * 8;
    bf16x8 bv8 = *reinterpret_cast<const bf16x8*>(Brow + f);
    if (!bvalid) bv8 = zero8;
    #pragma unroll
    for (int i = 0; i < 2; ++i) {
      const bf16x8 av8 = *reinterpret_cast<const bf16x8*>(
          Az + (size_t)(sbase + i * 16 + lr) * GF + f);
      acc[i] = __builtin_amdgcn_mfma_f32_16x16x32_bf16(av8, bv8, acc[i], 0, 0, 0);
    }
  }

  // write raw logits^T; per-lane stats over this lane's 8 s values (col n = lr)
  float* PTz = PT + (size_t)z * SS * 16;
  float mx = -3.0e38f;
  #pragma unroll
  for (int i = 0; i < 2; ++i)
    #pragma unroll
    for (int reg = 0; reg < 4; ++reg) {
      const int s = sbase + i * 16 + quad * 4 + reg;
      if (s < SS) {
        PTz[s * 16 + lr] = acc[i][reg];
        mx = fmaxf(mx, acc[i][reg]);
      }
    }
  float l = 0.f;
  #pragma unroll
  for (int i = 0; i < 2; ++i)
    #pragma unroll
    for (int reg = 0; reg < 4; ++reg) {
      const int s = sbase + i * 16 + quad * 4 + reg;
      if (s < SS) l += __expf(acc[i][reg] - mx);
    }
  // merge across the 4 quads holding the same n
  #pragma unroll
  for (int d = 16; d < 64; d <<= 1) {
    const float om = __shfl_xor(mx, d, 64);
    const float ol = __shfl_xor(l, d, 64);
    const float M = fmaxf(mx, om);
    l = l * __expf(mx - M) + ol * __expf(om - M);
    mx = M;
  }
  if (lane < 16) { redm[wave][lr] = mx; redl[wave][lr] = l; }
  __syncthreads();
  if (tid < 16) {
    float M = -3.0e38f;
    #pragma unroll
    for (int w = 0; w < 4; ++w) M = fmaxf(M, redm[w][tid]);
    float L = 0.f;
    #pragma unroll
    for (int w = 0; w < 4; ++w) L += redl[w][tid] * __expf(redm[w][tid] - M);
    pstat[((size_t)z * 13 + blk) * 32 + tid]      = M;
    pstat[((size_t)z * 13 + blk) * 32 + 16 + tid] = L;
  }
}

// combine 13 block stats -> mstat[z][0..15]=M, [16..31]=1/L
__global__ __launch_bounds__(256) void stat_combine(const float* __restrict__ pstat,
                                                    float* __restrict__ mstat) {
  const int idx = blockIdx.x * 256 + threadIdx.x;
  if (idx >= 64 * 16) return;
  const int z = idx >> 4, n = idx & 15;
  float M = -3.0e38f;
  #pragma unroll
  for (int cc = 0; cc < 13; ++cc) M = fmaxf(M, pstat[((size_t)z * 13 + cc) * 32 + n]);
  float L = 0.f;
  #pragma unroll
  for (int cc = 0; cc < 13; ++cc)
    L += pstat[((size_t)z * 13 + cc) * 32 + 16 + n] *
         __expf(pstat[((size_t)z * 13 + cc) * 32 + n] - M);
  mstat[(z << 5) + n]      = M;
  mstat[(z << 5) + 16 + n] = 1.0f / L;
}

// ---------------- upd: O[n][f] += sum_s P[s][n] * ctxT[s][f] ----------------
// grid (4 fc, 4 sc, 64 z), block 256. Coalesced ctxT staging, atomic partial O.
__global__ __launch_bounds__(256) void upd_part(
    const unsigned short* __restrict__ ctxT, const float* __restrict__ PT,
    const float* __restrict__ mstat, float* __restrict__ flatacc)
{
  __shared__ float Bs[32][65];
  __shared__ float Ps[32][17];
  __shared__ float sm[16], sil[16];
  const int fc = blockIdx.x, sc = blockIdx.y, z = blockIdx.z;
  const int g = z >> 4, b = z & 15;
  const int count = c_counts[b], off = c_offs[b];
  const int f0 = fc << 6;
  const int t0 = c_t0[sc], t1 = c_t1[sc];
  const unsigned short* Az = ctxT + (size_t)z * SPAD * GF;
  const float* PTz = PT + (size_t)z * SS * 16;
  const int tid = threadIdx.x;
  if (tid < 16) sm[tid] = mstat[(z << 5) + tid];
  else if (tid < 32) sil[tid - 16] = mstat[(z << 5) + tid];
  __syncthreads();

  const int TX = tid & 63, TY = tid >> 6;
  float o[4] = {};
  for (int t = t0; t < t1; ++t) {
    const int s0 = t * 32;
    #pragma unroll
    for (int q = 0; q < 2; ++q) {
      const int idx = q * 256 + tid;
      const int nn = idx & 15, ss = idx >> 4;
      Ps[ss][nn] = __expf(PTz[(s0 + ss) * 16 + nn] - sm[nn]) * sil[nn];
    }
    #pragma unroll
    for (int q = 0; q < 4; ++q) {
      const int idx = q * 256 + tid;
      const int f2 = idx & 31, ss = idx >> 5;
      const unsigned pair = *reinterpret_cast<const unsigned*>(
          Az + (size_t)(s0 + ss) * GF + f0 + f2 * 2);
      Bs[ss][f2 * 2]     = bf2f((unsigned short)(pair & 0xFFFF));
      Bs[ss][f2 * 2 + 1] = bf2f((unsigned short)(pair >> 16));
    }
    __syncthreads();
    #pragma unroll
    for (int k = 0; k < 32; ++k) {
      const float bv = Bs[k][TX];
      #pragma unroll
      for (int i = 0; i < 4; ++i)
        o[i] = fmaf(Ps[k][(TY << 2) + i], bv, o[i]);
    }
    __syncthreads();
  }
  #pragma unroll
  for (int i = 0; i < 4; ++i) {
    const int n = (TY << 2) + i;
    if (n < count) {
      const int t = off + n;
      const int col = (g << 8) + f0 + TX;
      atomicAdd(&flatacc[t * INDIM + col], o[i]);
    }
  }
}

extern "C" void kernel_launch(void* const* d_in, const int* in_sizes, int n_in,
                              void* d_out, int out_size, void* d_ws, size_t ws_size,
                              hipStream_t stream) {
  (void)in_sizes; (void)n_in; (void)out_size; (void)ws_size;
  const float* actor = (const float*)d_in[0];
  const float* fmap  = (const float*)d_in[1];
  const float* W_a   = (const float*)d_in[2];
  const float* b_a   = (const float*)d_in[3];
  const float* W_c   = (const float*)d_in[4];
  const float* b_c   = (const float*)d_in[5];
  const float* W_h   = (const float*)d_in[6];
  float* out = (float*)d_out;
  char* ws = (char*)d_ws;

  float* emb             = (float*)(ws);                        // 655,360 B
  float* flatacc         = (float*)(ws + 655360);               // 655,360 B (adjacent to emb)
  unsigned short* flat_h = (unsigned short*)(ws + 1310720);     // 327,680 B
  unsigned short* emb_h  = (unsigned short*)(ws + 1638400);     // 327,680 B
  float* mstat           = (float*)(ws + 1966080);              //   8,192 B
  float* PT              = (float*)(ws + 1974272);              // 6,422,528 B
  unsigned short* ctxT   = (unsigned short*)(ws + 8396800);     // 64*1664*256*2 = 54,525,952 B
  unsigned short* Ah     = (unsigned short*)(ws + 62922752);    // 1,769,472 B
  float* pstat           = (float*)(ws + 62922752);             // 106,496 B (aliases Ah, time-disjoint)
  unsigned short* BhT    = (unsigned short*)(ws + 64692224);    // 43,352,064 B
  unsigned short* Wh_h   = (unsigned short*)(ws + 108044288);   // 524,288 B  (end 108,568,576)

  // 0) conversions + zeroing
  hipLaunchKernelGGL(wc_to_bf16, dim3((4 * 256 * KPAD + 255) / 256), dim3(256), 0, stream,
                     W_c, Ah);
  hipLaunchKernelGGL(fm_to_bf16T, dim3(49, 27, 16), dim3(256), 0, stream, fmap, BhT);
  hipLaunchKernelGGL(pack_bf16, dim3(256), dim3(256), 0, stream, W_h, Wh_h, 65536);
  hipLaunchKernelGGL(zero_f32, dim3(1280), dim3(256), 0, stream, emb, 2 * TOTAL * INDIM);

  // 1) emb = actor @ W_a^T + b_a (fp32 split-K x4) ; pack bf16 copy for adj
  hipLaunchKernelGGL(emb_splitk, dim3(16, 3, 4), dim3(256), 0, stream,
                     actor, W_a, b_a, emb);
  hipLaunchKernelGGL(pack_bf16, dim3(160), dim3(256), 0, stream, emb, emb_h, 40960);

  // 2) ctxT via bf16 MFMA (swapped operands -> [z][s][f], f-contig)
  hipLaunchKernelGGL(ctx_mfma, dim3(2, 13, 64), dim3(256), 0, stream, Ah, BhT, b_c, ctxT);

  // 3) adj logits via MFMA -> PT + partial stats; combine
  hipLaunchKernelGGL(adj_mfma, dim3(13, 64), dim3(256), 0, stream, ctxT, emb_h, PT, pstat);
  hipLaunchKernelGGL(stat_combine, dim3(4), dim3(256), 0, stream, pstat, mstat);

  // 4) upd (f-split 4 x s-split 4) -> atomic partial O in flatacc
  hipLaunchKernelGGL(upd_part, dim3(4, 4, 64), dim3(256), 0, stream,
                     ctxT, PT, mstat, flatacc);

  // 4b) flat_h = bf16(flatacc + emb)
  hipLaunchKernelGGL(pack_flat, dim3(640), dim3(256), 0, stream, flatacc, emb, flat_h);

  // 5) out = relu(flat @ W_h^T) via bf16 MFMA
  hipLaunchKernelGGL(head_mfma, dim3(4, 3, 4), dim3(256), 0, stream, flat_h, Wh_h, out);
}